// Round 1
// baseline (6679.051 us; speedup 1.0000x reference)
//
#include <hip/hip_runtime.h>
#include <hip/hip_bf16.h>

// MPNN: N=100000 nodes, E=1600000 edges, D=128, L=4, G=64.
// Strategy:
//   h = cat(x,pos)@Win + bin
//   per layer: P = h@W1a, Q = h@W1b  (node GEMMs)
//     edge tile kernel: t = relu(P[dst]+Q[src]+ea@W1c+b1); m = relu(t@W2f+b2f)
//     (BN folded into W2f/b2f); segmented scatter-add into aggr (edges counting-
//     sorted by dst once per call -> plain stores for interior dst, atomics at
//     tile boundaries only)
//   update: u1 = relu(h@U1a + aggr@U1b + ub1); h += relu(u1@U2f + ub2f)
//   pool: segment mean over sorted batch, then @pred_w + pred_b.

#define EPSBN 1e-5f

// ---------------- fold BN into second linear ----------------
__global__ __launch_bounds__(128) void fold_kernel(
    const float* __restrict__ mw2, const float* __restrict__ mb2,
    const float* __restrict__ mg, const float* __restrict__ mb,
    const float* __restrict__ mm, const float* __restrict__ mv,
    const float* __restrict__ uw2, const float* __restrict__ ub2,
    const float* __restrict__ ug, const float* __restrict__ ub,
    const float* __restrict__ um, const float* __restrict__ uv,
    float* __restrict__ mW2f, float* __restrict__ mB2f,
    float* __restrict__ uW2f, float* __restrict__ uB2f) {
  int l = blockIdx.x & 3;
  bool isu = blockIdx.x >= 4;
  const float* W2 = (isu ? uw2 : mw2) + (size_t)l * 128 * 128;
  const float* b2 = (isu ? ub2 : mb2) + l * 128;
  const float* gg = (isu ? ug : mg) + l * 128;
  const float* bb = (isu ? ub : mb) + l * 128;
  const float* mn = (isu ? um : mm) + l * 128;
  const float* vr = (isu ? uv : mv) + l * 128;
  float* Wf = (isu ? uW2f : mW2f) + (size_t)l * 128 * 128;
  float* Bf = (isu ? uB2f : mB2f) + l * 128;
  __shared__ float a[128], c[128];
  int d = threadIdx.x;
  float ad = gg[d] * rsqrtf(vr[d] + EPSBN);
  a[d] = ad;
  c[d] = bb[d] - mn[d] * ad;
  __syncthreads();
  float acc = b2[d];
  for (int k = 0; k < 128; ++k) {
    float w = W2[k * 128 + d];
    Wf[k * 128 + d] = a[k] * w;
    acc = fmaf(c[k], w, acc);
  }
  Bf[d] = acc;
}

// ---------------- input projection ----------------
__global__ __launch_bounds__(256) void lin_in_kernel(
    const float* __restrict__ x, const float* __restrict__ pos,
    const float* __restrict__ W, const float* __restrict__ b,
    float* __restrict__ h, int Nn) {
  int gi = blockIdx.x * 256 + threadIdx.x;
  if (gi >= Nn * 128) return;
  int n = gi >> 7, d = gi & 127;
  float acc = b[d];
#pragma unroll
  for (int j = 0; j < 11; ++j) acc = fmaf(x[(size_t)n * 11 + j], W[j * 128 + d], acc);
#pragma unroll
  for (int j = 0; j < 3; ++j) acc = fmaf(pos[(size_t)n * 3 + j], W[(11 + j) * 128 + d], acc);
  h[gi] = acc;
}

// ---------------- counting sort of edges by dst ----------------
__global__ __launch_bounds__(256) void hist_kernel(const int* __restrict__ dst, int* __restrict__ count, int Ee) {
  int i = blockIdx.x * 256 + threadIdx.x;
  if (i < Ee) atomicAdd(&count[dst[i]], 1);
}

__global__ __launch_bounds__(1024) void scan_kernel(const int* __restrict__ count, int* __restrict__ cursor, int n) {
  __shared__ int buf[1024];
  __shared__ int carry;
  if (threadIdx.x == 0) carry = 0;
  __syncthreads();
  for (int base = 0; base < n; base += 1024) {
    int i = base + threadIdx.x;
    int v = (i < n) ? count[i] : 0;
    buf[threadIdx.x] = v;
    __syncthreads();
    for (int off = 1; off < 1024; off <<= 1) {
      int t = (threadIdx.x >= off) ? buf[threadIdx.x - off] : 0;
      __syncthreads();
      buf[threadIdx.x] += t;
      __syncthreads();
    }
    int incl = buf[threadIdx.x];
    if (i < n) cursor[i] = carry + incl - v;  // exclusive
    __syncthreads();
    if (threadIdx.x == 1023) carry += buf[1023];
    __syncthreads();
  }
}

__global__ __launch_bounds__(256) void scatter_kernel(
    const int* __restrict__ src, const int* __restrict__ dst, const float* __restrict__ ea,
    int* __restrict__ cursor, int* __restrict__ dst_s, int* __restrict__ src_s,
    float* __restrict__ ea_s, int Ee) {
  int e = blockIdx.x * 256 + threadIdx.x;
  if (e >= Ee) return;
  int dn = dst[e];
  int pos = atomicAdd(&cursor[dn], 1);
  dst_s[pos] = dn;
  src_s[pos] = src[e];
  *(float4*)(ea_s + (size_t)pos * 4) = *(const float4*)(ea + (size_t)e * 4);
}

// ---------------- generic node GEMM: [M,128]x[128,128] ----------------
// mode 0: C = A@B + bias ; mode 1: C = relu(C + A@B + bias) ; mode 2: C += relu(A@B + bias)
__global__ __launch_bounds__(256) void gemm128(
    const float* __restrict__ A, const float* __restrict__ B,
    const float* __restrict__ bias, float* __restrict__ C, int M, int mode) {
  __shared__ float As[64][128];
  __shared__ float Bs[16][128];
  __shared__ float bs[128];
  const int tid = threadIdx.x;
  const int row0 = blockIdx.x * 64;
#pragma unroll
  for (int i = 0; i < 8; ++i) {
    int idx = tid + i * 256;
    int r = idx >> 5, c4 = (idx & 31) << 2;
    float4 v = make_float4(0.f, 0.f, 0.f, 0.f);
    if (row0 + r < M) v = *(const float4*)(A + (size_t)(row0 + r) * 128 + c4);
    *(float4*)&As[r][c4] = v;
  }
  if (tid < 128) bs[tid] = (bias != nullptr) ? bias[tid] : 0.f;
  const int dg = tid & 31, rg = tid >> 5;
  const int d0 = dg << 2, r0 = rg << 3;
  float acc[8][4];
#pragma unroll
  for (int r = 0; r < 8; ++r) { acc[r][0] = acc[r][1] = acc[r][2] = acc[r][3] = 0.f; }
  for (int k0 = 0; k0 < 128; k0 += 16) {
    __syncthreads();
#pragma unroll
    for (int i = 0; i < 2; ++i) {
      int idx = tid + i * 256;
      int kk = idx >> 5, c4 = (idx & 31) << 2;
      *(float4*)&Bs[kk][c4] = *(const float4*)(B + (size_t)(k0 + kk) * 128 + c4);
    }
    __syncthreads();
#pragma unroll
    for (int kk = 0; kk < 16; ++kk) {
      float4 bv = *(float4*)&Bs[kk][d0];
#pragma unroll
      for (int r = 0; r < 8; ++r) {
        float a = As[r0 + r][k0 + kk];
        acc[r][0] = fmaf(a, bv.x, acc[r][0]);
        acc[r][1] = fmaf(a, bv.y, acc[r][1]);
        acc[r][2] = fmaf(a, bv.z, acc[r][2]);
        acc[r][3] = fmaf(a, bv.w, acc[r][3]);
      }
    }
  }
  float4 bb = *(float4*)&bs[d0];
#pragma unroll
  for (int r = 0; r < 8; ++r) {
    int row = row0 + r0 + r;
    if (row >= M) break;
    float* cp = C + (size_t)row * 128 + d0;
    float rx = acc[r][0] + bb.x, ry = acc[r][1] + bb.y;
    float rz = acc[r][2] + bb.z, rw = acc[r][3] + bb.w;
    float4 o;
    if (mode == 0) {
      o = make_float4(rx, ry, rz, rw);
    } else if (mode == 1) {
      float4 cv = *(float4*)cp;
      o = make_float4(fmaxf(cv.x + rx, 0.f), fmaxf(cv.y + ry, 0.f),
                      fmaxf(cv.z + rz, 0.f), fmaxf(cv.w + rw, 0.f));
    } else {
      float4 cv = *(float4*)cp;
      o = make_float4(cv.x + fmaxf(rx, 0.f), cv.y + fmaxf(ry, 0.f),
                      cv.z + fmaxf(rz, 0.f), cv.w + fmaxf(rw, 0.f));
    }
    *(float4*)cp = o;
  }
}

// ---------------- edge message kernel ----------------
// Per 64-edge tile (edges sorted by dst):
//   t = relu(P[dst] + Q[src] + ea@W1c + b1)  -> LDS
//   m = relu(t @ W2f + b2f)                  -> registers -> LDS
//   segmented sum over equal-dst runs -> aggr (plain store interior, atomic boundary)
__global__ __launch_bounds__(256) void edge_kernel(
    const float* __restrict__ P, const float* __restrict__ Q,
    const float* __restrict__ ea_s, const int* __restrict__ dst_s, const int* __restrict__ src_s,
    const float* __restrict__ W1c, const float* __restrict__ b1,
    const float* __restrict__ W2f, const float* __restrict__ B2f,
    float* __restrict__ aggr, int Ee) {
  __shared__ float Ts[64][128];
  __shared__ float Ws[16][128];
  __shared__ float w1c[4][128];
  __shared__ float sb1[128], sb2[128];
  __shared__ int sdst[64], ssrc[64];
  const int tid = threadIdx.x;
  const int e0 = blockIdx.x * 64;
  if (tid < 128) { sb1[tid] = b1[tid]; sb2[tid] = B2f[tid]; }
  for (int i = tid; i < 512; i += 256) w1c[i >> 7][i & 127] = W1c[i];
  if (tid < 64) {
    int e = e0 + tid;
    sdst[tid] = (e < Ee) ? dst_s[e] : -1;
    ssrc[tid] = (e < Ee) ? src_s[e] : 0;
  }
  __syncthreads();
  const int dg = tid & 31, rg = tid >> 5;
  const int d0 = dg << 2, el0 = rg << 3;
  // Phase A: build T tile
#pragma unroll
  for (int i = 0; i < 8; ++i) {
    int el = el0 + i;
    int dn = sdst[el];
    float4 t = make_float4(0.f, 0.f, 0.f, 0.f);
    if (dn >= 0) {
      int sn = ssrc[el];
      float4 p = *(const float4*)(P + (size_t)dn * 128 + d0);
      float4 q = *(const float4*)(Q + (size_t)sn * 128 + d0);
      float4 ev = *(const float4*)(ea_s + (size_t)(e0 + el) * 4);
      t.x = p.x + q.x + sb1[d0 + 0];
      t.y = p.y + q.y + sb1[d0 + 1];
      t.z = p.z + q.z + sb1[d0 + 2];
      t.w = p.w + q.w + sb1[d0 + 3];
      t.x = fmaf(ev.x, w1c[0][d0 + 0], fmaf(ev.y, w1c[1][d0 + 0], fmaf(ev.z, w1c[2][d0 + 0], fmaf(ev.w, w1c[3][d0 + 0], t.x))));
      t.y = fmaf(ev.x, w1c[0][d0 + 1], fmaf(ev.y, w1c[1][d0 + 1], fmaf(ev.z, w1c[2][d0 + 1], fmaf(ev.w, w1c[3][d0 + 1], t.y))));
      t.z = fmaf(ev.x, w1c[0][d0 + 2], fmaf(ev.y, w1c[1][d0 + 2], fmaf(ev.z, w1c[2][d0 + 2], fmaf(ev.w, w1c[3][d0 + 2], t.z))));
      t.w = fmaf(ev.x, w1c[0][d0 + 3], fmaf(ev.y, w1c[1][d0 + 3], fmaf(ev.z, w1c[2][d0 + 3], fmaf(ev.w, w1c[3][d0 + 3], t.w))));
      t.x = fmaxf(t.x, 0.f); t.y = fmaxf(t.y, 0.f); t.z = fmaxf(t.z, 0.f); t.w = fmaxf(t.w, 0.f);
    }
    *(float4*)&Ts[el][d0] = t;
  }
  // Phase B: m = T @ W2f
  float acc[8][4];
#pragma unroll
  for (int r = 0; r < 8; ++r) { acc[r][0] = acc[r][1] = acc[r][2] = acc[r][3] = 0.f; }
  for (int k0 = 0; k0 < 128; k0 += 16) {
    __syncthreads();
#pragma unroll
    for (int i = 0; i < 2; ++i) {
      int idx = tid + i * 256;
      int kk = idx >> 5, c4 = (idx & 31) << 2;
      *(float4*)&Ws[kk][c4] = *(const float4*)(W2f + (size_t)(k0 + kk) * 128 + c4);
    }
    __syncthreads();
#pragma unroll
    for (int kk = 0; kk < 16; ++kk) {
      float4 bv = *(float4*)&Ws[kk][d0];
#pragma unroll
      for (int r = 0; r < 8; ++r) {
        float a = Ts[el0 + r][k0 + kk];
        acc[r][0] = fmaf(a, bv.x, acc[r][0]);
        acc[r][1] = fmaf(a, bv.y, acc[r][1]);
        acc[r][2] = fmaf(a, bv.z, acc[r][2]);
        acc[r][3] = fmaf(a, bv.w, acc[r][3]);
      }
    }
  }
  __syncthreads();
  // write m (bias+relu) back into Ts
  float4 b2v = *(float4*)&sb2[d0];
#pragma unroll
  for (int r = 0; r < 8; ++r) {
    float4 o = make_float4(fmaxf(acc[r][0] + b2v.x, 0.f), fmaxf(acc[r][1] + b2v.y, 0.f),
                           fmaxf(acc[r][2] + b2v.z, 0.f), fmaxf(acc[r][3] + b2v.w, 0.f));
    *(float4*)&Ts[el0 + r][d0] = o;
  }
  __syncthreads();
  // Phase C: segmented reduce over equal-dst runs
  const int d = tid & 127, half = tid >> 7;
  const int dfirst = sdst[0], dlast = sdst[63];
  for (int s = half; s < 64; s += 2) {
    int dn = sdst[s];
    if (dn < 0) continue;
    if (s > 0 && sdst[s - 1] == dn) continue;  // not a segment start
    float sum = 0.f;
    int e = s;
    do { sum += Ts[e][d]; ++e; } while (e < 64 && sdst[e] == dn);
    float* ap = aggr + (size_t)dn * 128 + d;
    if (dn == dfirst || dn == dlast) atomicAdd(ap, sum);
    else *ap = sum;  // all edges of dn are inside this tile
  }
}

// ---------------- pooling ----------------
__global__ __launch_bounds__(128) void pool_sum_kernel(
    const float* __restrict__ h, const int* __restrict__ batch,
    float* __restrict__ sums, int* __restrict__ gcnt, int Nn) {
  int n0 = blockIdx.x * 256;
  if (n0 >= Nn) return;
  int nend = min(n0 + 256, Nn);
  int d = threadIdx.x;
  int gcur = batch[n0];
  float run = 0.f;
  int cnt = 0;
  for (int n = n0; n < nend; ++n) {
    int g = batch[n];
    if (g != gcur) {
      atomicAdd(&sums[(size_t)gcur * 128 + d], run);
      if (d == 0) atomicAdd(&gcnt[gcur], cnt);
      run = 0.f; cnt = 0; gcur = g;
    }
    run += h[(size_t)n * 128 + d];
    cnt += 1;
  }
  atomicAdd(&sums[(size_t)gcur * 128 + d], run);
  if (d == 0) atomicAdd(&gcnt[gcur], cnt);
}

__global__ __launch_bounds__(128) void pred_kernel(
    const float* __restrict__ sums, const int* __restrict__ gcnt,
    const float* __restrict__ pw, const float* __restrict__ pb, float* __restrict__ out) {
  __shared__ float red[2];
  int g = blockIdx.x, d = threadIdx.x;
  float c = fmaxf((float)gcnt[g], 1.f);
  float v = (sums[(size_t)g * 128 + d] / c) * pw[d];
  for (int o = 32; o > 0; o >>= 1) v += __shfl_down(v, o, 64);
  if ((d & 63) == 0) red[d >> 6] = v;
  __syncthreads();
  if (d == 0) out[g] = red[0] + red[1] + pb[0];
}

// ---------------- launch ----------------
extern "C" void kernel_launch(void* const* d_in, const int* in_sizes, int n_in,
                              void* d_out, int out_size, void* d_ws, size_t ws_size,
                              hipStream_t stream) {
  const float* x = (const float*)d_in[0];
  const float* pos = (const float*)d_in[1];
  const int* ei = (const int*)d_in[2];
  const float* ea = (const float*)d_in[3];
  const int* batch = (const int*)d_in[4];
  const float* lin_w = (const float*)d_in[5];
  const float* lin_b = (const float*)d_in[6];
  const float* mw1 = (const float*)d_in[7];
  const float* mb1 = (const float*)d_in[8];
  const float* mg = (const float*)d_in[9];
  const float* mbb = (const float*)d_in[10];
  const float* mm = (const float*)d_in[11];
  const float* mv = (const float*)d_in[12];
  const float* mw2 = (const float*)d_in[13];
  const float* mb2 = (const float*)d_in[14];
  const float* uw1 = (const float*)d_in[15];
  const float* ub1 = (const float*)d_in[16];
  const float* ug = (const float*)d_in[17];
  const float* ubb = (const float*)d_in[18];
  const float* um = (const float*)d_in[19];
  const float* uv = (const float*)d_in[20];
  const float* uw2 = (const float*)d_in[21];
  const float* ub2 = (const float*)d_in[22];
  const float* pw = (const float*)d_in[23];
  const float* pb = (const float*)d_in[24];
  float* out = (float*)d_out;

  const int Nn = in_sizes[0] / 11;
  const int Ee = in_sizes[3] / 4;
  const int* srcp = ei;        // edge_index[0] = source j
  const int* dstp = ei + Ee;   // edge_index[1] = target i

  char* wsb = (char*)d_ws;
  size_t off = 0;
  auto alloc = [&](size_t bytes) -> void* {
    void* p = wsb + off;
    off = (off + bytes + 255) & ~(size_t)255;
    return p;
  };
  float* h = (float*)alloc((size_t)Nn * 128 * 4);
  float* Pb = (float*)alloc((size_t)Nn * 128 * 4);
  float* Qb = (float*)alloc((size_t)Nn * 128 * 4);
  float* aggr = (float*)alloc((size_t)Nn * 128 * 4);
  int* dst_s = (int*)alloc((size_t)Ee * 4);
  int* src_s = (int*)alloc((size_t)Ee * 4);
  float* ea_s = (float*)alloc((size_t)Ee * 16);
  int* count = (int*)alloc((size_t)Nn * 4);
  int* cursor = (int*)alloc((size_t)Nn * 4);
  float* mW2f = (float*)alloc((size_t)4 * 128 * 128 * 4);
  float* mB2f = (float*)alloc((size_t)4 * 128 * 4);
  float* uW2f = (float*)alloc((size_t)4 * 128 * 128 * 4);
  float* uB2f = (float*)alloc((size_t)4 * 128 * 4);
  float* sums = (float*)alloc((size_t)out_size * 128 * 4);
  int* gcnt = (int*)alloc((size_t)out_size * 4);
  (void)ws_size; (void)n_in;

  fold_kernel<<<8, 128, 0, stream>>>(mw2, mb2, mg, mbb, mm, mv,
                                     uw2, ub2, ug, ubb, um, uv,
                                     mW2f, mB2f, uW2f, uB2f);
  lin_in_kernel<<<(Nn * 128 + 255) / 256, 256, 0, stream>>>(x, pos, lin_w, lin_b, h, Nn);

  hipMemsetAsync(count, 0, (size_t)Nn * 4, stream);
  hist_kernel<<<(Ee + 255) / 256, 256, 0, stream>>>(dstp, count, Ee);
  scan_kernel<<<1, 1024, 0, stream>>>(count, cursor, Nn);
  scatter_kernel<<<(Ee + 255) / 256, 256, 0, stream>>>(srcp, dstp, ea, cursor,
                                                       dst_s, src_s, ea_s, Ee);

  const int gblocks = (Nn + 63) / 64;
  for (int l = 0; l < 4; ++l) {
    const float* W1 = mw1 + (size_t)l * 260 * 128;
    gemm128<<<gblocks, 256, 0, stream>>>(h, W1, nullptr, Pb, Nn, 0);                 // P = h@W1a
    gemm128<<<gblocks, 256, 0, stream>>>(h, W1 + 128 * 128, nullptr, Qb, Nn, 0);     // Q = h@W1b
    hipMemsetAsync(aggr, 0, (size_t)Nn * 128 * 4, stream);
    edge_kernel<<<(Ee + 63) / 64, 256, 0, stream>>>(Pb, Qb, ea_s, dst_s, src_s,
                                                    W1 + 256 * 128, mb1 + l * 128,
                                                    mW2f + (size_t)l * 16384, mB2f + l * 128,
                                                    aggr, Ee);
    const float* U1 = uw1 + (size_t)l * 256 * 128;
    gemm128<<<gblocks, 256, 0, stream>>>(h, U1, ub1 + l * 128, Pb, Nn, 0);           // tmp = h@U1a + ub1
    gemm128<<<gblocks, 256, 0, stream>>>(aggr, U1 + 128 * 128, nullptr, Pb, Nn, 1);  // tmp = relu(tmp + aggr@U1b)
    gemm128<<<gblocks, 256, 0, stream>>>(Pb, uW2f + (size_t)l * 16384, uB2f + l * 128, h, Nn, 2); // h += relu(...)
  }

  hipMemsetAsync(sums, 0, (size_t)out_size * 128 * 4, stream);
  hipMemsetAsync(gcnt, 0, (size_t)out_size * 4, stream);
  pool_sum_kernel<<<(Nn + 255) / 256, 128, 0, stream>>>(h, batch, sums, gcnt, Nn);
  pred_kernel<<<out_size, 128, 0, stream>>>(sums, gcnt, pw, pb, out);
}

// Round 2
// 3893.496 us; speedup vs baseline: 1.7154x; 1.7154x over previous
//
#include <hip/hip_runtime.h>
#include <hip/hip_bf16.h>

// MPNN: N=100000 nodes, E=1600000 edges, D=128, L=4, G=64.
//   h = cat(x,pos)@Win + bin
//   per layer: P = h@W1a, Q = h@W1b  (node GEMMs, fp32)
//     edge tile kernel: t = relu(P[dst]+Q[src]+ea@W1c+b1)  [fp32 -> bf16 LDS]
//                       m = relu(t@W2f+b2f)                [MFMA bf16, B frags
//                       loaded from global pre-transposed bf16 W2fT]
//     segmented scatter-add into aggr (edges counting-sorted by dst; plain
//     stores for tile-interior dst, atomics only at tile boundaries)
//   update: u1 = relu(h@U1a + aggr@U1b + ub1); h += relu(u1@U2f + ub2f) (fp32)
//   pool: segment mean over sorted batch, then @pred_w + pred_b.

#define EPSBN 1e-5f

typedef __bf16 bf16x8 __attribute__((ext_vector_type(8)));
typedef float floatx4 __attribute__((ext_vector_type(4)));

static __device__ __forceinline__ unsigned short f2b(float f) {
  union { float f; unsigned u; } v; v.f = f;
  unsigned u = v.u;
  return (unsigned short)((u + 0x7fffu + ((u >> 16) & 1u)) >> 16);  // RNE
}

// ---------------- fold BN into second linear ----------------
__global__ __launch_bounds__(128) void fold_kernel(
    const float* __restrict__ mw2, const float* __restrict__ mb2,
    const float* __restrict__ mg, const float* __restrict__ mb,
    const float* __restrict__ mm, const float* __restrict__ mv,
    const float* __restrict__ uw2, const float* __restrict__ ub2,
    const float* __restrict__ ug, const float* __restrict__ ub,
    const float* __restrict__ um, const float* __restrict__ uv,
    float* __restrict__ mB2f, unsigned short* __restrict__ mW2fT,
    float* __restrict__ uW2f, float* __restrict__ uB2f) {
  int l = blockIdx.x & 3;
  bool isu = blockIdx.x >= 4;
  const float* W2 = (isu ? uw2 : mw2) + (size_t)l * 128 * 128;
  const float* b2 = (isu ? ub2 : mb2) + l * 128;
  const float* gg = (isu ? ug : mg) + l * 128;
  const float* bb = (isu ? ub : mb) + l * 128;
  const float* mn = (isu ? um : mm) + l * 128;
  const float* vr = (isu ? uv : mv) + l * 128;
  __shared__ float a[128], c[128];
  int d = threadIdx.x;
  float ad = gg[d] * rsqrtf(vr[d] + EPSBN);
  a[d] = ad;
  c[d] = bb[d] - mn[d] * ad;
  __syncthreads();
  float acc = b2[d];
  if (isu) {
    float* Wf = uW2f + (size_t)l * 128 * 128;
    for (int k = 0; k < 128; ++k) {
      float w = W2[k * 128 + d];
      Wf[k * 128 + d] = a[k] * w;
      acc = fmaf(c[k], w, acc);
    }
    uB2f[l * 128 + d] = acc;
  } else {
    unsigned short* WfT = mW2fT + (size_t)l * 128 * 128;
    for (int k = 0; k < 128; ++k) {
      float w = W2[k * 128 + d];
      WfT[(size_t)d * 128 + k] = f2b(a[k] * w);  // [n][k] bf16
      acc = fmaf(c[k], w, acc);
    }
    mB2f[l * 128 + d] = acc;
  }
}

// ---------------- input projection ----------------
__global__ __launch_bounds__(256) void lin_in_kernel(
    const float* __restrict__ x, const float* __restrict__ pos,
    const float* __restrict__ W, const float* __restrict__ b,
    float* __restrict__ h, int Nn) {
  int gi = blockIdx.x * 256 + threadIdx.x;
  if (gi >= Nn * 128) return;
  int n = gi >> 7, d = gi & 127;
  float acc = b[d];
#pragma unroll
  for (int j = 0; j < 11; ++j) acc = fmaf(x[(size_t)n * 11 + j], W[j * 128 + d], acc);
#pragma unroll
  for (int j = 0; j < 3; ++j) acc = fmaf(pos[(size_t)n * 3 + j], W[(11 + j) * 128 + d], acc);
  h[gi] = acc;
}

// ---------------- counting sort of edges by dst ----------------
__global__ __launch_bounds__(256) void hist_kernel(const int* __restrict__ dst, int* __restrict__ count, int Ee) {
  int i = blockIdx.x * 256 + threadIdx.x;
  if (i < Ee) atomicAdd(&count[dst[i]], 1);
}

__global__ __launch_bounds__(1024) void scan_kernel(const int* __restrict__ count, int* __restrict__ cursor, int n) {
  __shared__ int buf[1024];
  __shared__ int carry;
  if (threadIdx.x == 0) carry = 0;
  __syncthreads();
  for (int base = 0; base < n; base += 1024) {
    int i = base + threadIdx.x;
    int v = (i < n) ? count[i] : 0;
    buf[threadIdx.x] = v;
    __syncthreads();
    for (int off = 1; off < 1024; off <<= 1) {
      int t = (threadIdx.x >= off) ? buf[threadIdx.x - off] : 0;
      __syncthreads();
      buf[threadIdx.x] += t;
      __syncthreads();
    }
    int incl = buf[threadIdx.x];
    if (i < n) cursor[i] = carry + incl - v;  // exclusive
    __syncthreads();
    if (threadIdx.x == 1023) carry += buf[1023];
    __syncthreads();
  }
}

__global__ __launch_bounds__(256) void scatter_kernel(
    const int* __restrict__ src, const int* __restrict__ dst, const float* __restrict__ ea,
    int* __restrict__ cursor, int* __restrict__ dst_s, int* __restrict__ src_s,
    float* __restrict__ ea_s, int Ee) {
  int e = blockIdx.x * 256 + threadIdx.x;
  if (e >= Ee) return;
  int dn = dst[e];
  int pos = atomicAdd(&cursor[dn], 1);
  dst_s[pos] = dn;
  src_s[pos] = src[e];
  *(float4*)(ea_s + (size_t)pos * 4) = *(const float4*)(ea + (size_t)e * 4);
}

// ---------------- generic node GEMM: [M,128]x[128,128] fp32 ----------------
// mode 0: C = A@B + bias ; mode 1: C = relu(C + A@B + bias) ; mode 2: C += relu(A@B + bias)
__global__ __launch_bounds__(256) void gemm128(
    const float* __restrict__ A, const float* __restrict__ B,
    const float* __restrict__ bias, float* __restrict__ C, int M, int mode) {
  __shared__ float As[64][128];
  __shared__ float Bs[16][128];
  __shared__ float bs[128];
  const int tid = threadIdx.x;
  const int row0 = blockIdx.x * 64;
#pragma unroll
  for (int i = 0; i < 8; ++i) {
    int idx = tid + i * 256;
    int r = idx >> 5, c4 = (idx & 31) << 2;
    float4 v = make_float4(0.f, 0.f, 0.f, 0.f);
    if (row0 + r < M) v = *(const float4*)(A + (size_t)(row0 + r) * 128 + c4);
    *(float4*)&As[r][c4] = v;
  }
  if (tid < 128) bs[tid] = (bias != nullptr) ? bias[tid] : 0.f;
  const int dg = tid & 31, rg = tid >> 5;
  const int d0 = dg << 2, r0 = rg << 3;
  float acc[8][4];
#pragma unroll
  for (int r = 0; r < 8; ++r) { acc[r][0] = acc[r][1] = acc[r][2] = acc[r][3] = 0.f; }
  for (int k0 = 0; k0 < 128; k0 += 16) {
    __syncthreads();
#pragma unroll
    for (int i = 0; i < 2; ++i) {
      int idx = tid + i * 256;
      int kk = idx >> 5, c4 = (idx & 31) << 2;
      *(float4*)&Bs[kk][c4] = *(const float4*)(B + (size_t)(k0 + kk) * 128 + c4);
    }
    __syncthreads();
#pragma unroll
    for (int kk = 0; kk < 16; ++kk) {
      float4 bv = *(float4*)&Bs[kk][d0];
#pragma unroll
      for (int r = 0; r < 8; ++r) {
        float a = As[r0 + r][k0 + kk];
        acc[r][0] = fmaf(a, bv.x, acc[r][0]);
        acc[r][1] = fmaf(a, bv.y, acc[r][1]);
        acc[r][2] = fmaf(a, bv.z, acc[r][2]);
        acc[r][3] = fmaf(a, bv.w, acc[r][3]);
      }
    }
  }
  float4 bb = *(float4*)&bs[d0];
#pragma unroll
  for (int r = 0; r < 8; ++r) {
    int row = row0 + r0 + r;
    if (row >= M) break;
    float* cp = C + (size_t)row * 128 + d0;
    float rx = acc[r][0] + bb.x, ry = acc[r][1] + bb.y;
    float rz = acc[r][2] + bb.z, rw = acc[r][3] + bb.w;
    float4 o;
    if (mode == 0) {
      o = make_float4(rx, ry, rz, rw);
    } else if (mode == 1) {
      float4 cv = *(float4*)cp;
      o = make_float4(fmaxf(cv.x + rx, 0.f), fmaxf(cv.y + ry, 0.f),
                      fmaxf(cv.z + rz, 0.f), fmaxf(cv.w + rw, 0.f));
    } else {
      float4 cv = *(float4*)cp;
      o = make_float4(cv.x + fmaxf(rx, 0.f), cv.y + fmaxf(ry, 0.f),
                      cv.z + fmaxf(rz, 0.f), cv.w + fmaxf(rw, 0.f));
    }
    *(float4*)cp = o;
  }
}

// ---------------- edge message kernel (MFMA bf16) ----------------
// 64 edges per block, 256 threads (4 waves).
//   Phase A: t = relu(P[dst]+Q[src]+ea@W1c+b1) fp32 -> bf16 LDS tile T[64][K=128]
//   Phase B: m = T @ W2fT^T via mfma_f32_16x16x32_bf16; B frags from global bf16.
//            wave w owns output cols [32w, 32w+32): 2 N-tiles x 4 M-tiles.
//   Phase C: m = relu(m + b2f) -> fp32 LDS -> segmented reduce over dst runs.
#define TS 136   // bf16 elements per T row (272 B = 17*16 B)
#define MSS 132  // floats per Ms row (528 B)
__global__ __launch_bounds__(256) void edge_kernel(
    const float* __restrict__ P, const float* __restrict__ Q,
    const float* __restrict__ ea_s, const int* __restrict__ dst_s, const int* __restrict__ src_s,
    const float* __restrict__ W1c, const float* __restrict__ b1,
    const unsigned short* __restrict__ W2fT, const float* __restrict__ B2f,
    float* __restrict__ aggr, int Ee) {
  __shared__ unsigned short Tl[64 * TS];
  __shared__ float Ms[64 * MSS];
  __shared__ int sdst[64], ssrc[64];
  const int tid = threadIdx.x;
  const int e0 = blockIdx.x * 64;
  if (tid < 64) {
    int e = e0 + tid;
    sdst[tid] = (e < Ee) ? dst_s[e] : -1;
    ssrc[tid] = (e < Ee) ? src_s[e] : 0;
  }

  const int lane = tid & 63;
  const int wv = tid >> 6;
  const int m16 = lane & 15;
  const int quad = lane >> 4;

  // B fragments from global (pre-transposed bf16 [n][k], L1/L2 hot)
  bf16x8 bB[2][4];
  {
    const __bf16* WT = (const __bf16*)W2fT;
#pragma unroll
    for (int ntl = 0; ntl < 2; ++ntl) {
      const __bf16* rp = WT + (size_t)(32 * wv + 16 * ntl + m16) * 128 + quad * 8;
#pragma unroll
      for (int kb = 0; kb < 4; ++kb) bB[ntl][kb] = *(const bf16x8*)(rp + kb * 32);
    }
  }

  __syncthreads();  // sdst/ssrc visible

  // ---- Phase A: build bf16 T tile ----
  const int dg = tid & 31, rg = tid >> 5;
  const int d0 = dg << 2, el0 = rg << 3;
  float4 b1v = *(const float4*)(b1 + d0);
  float4 w0 = *(const float4*)(W1c + 0 * 128 + d0);
  float4 w1 = *(const float4*)(W1c + 1 * 128 + d0);
  float4 w2 = *(const float4*)(W1c + 2 * 128 + d0);
  float4 w3 = *(const float4*)(W1c + 3 * 128 + d0);
#pragma unroll
  for (int i = 0; i < 8; ++i) {
    int el = el0 + i;
    int dn = sdst[el];
    ushort4 tb = make_ushort4(0, 0, 0, 0);
    if (dn >= 0) {
      int sn = ssrc[el];
      float4 p = *(const float4*)(P + (size_t)dn * 128 + d0);
      float4 q = *(const float4*)(Q + (size_t)sn * 128 + d0);
      float4 ev = *(const float4*)(ea_s + (size_t)(e0 + el) * 4);
      float tx = p.x + q.x + b1v.x, ty = p.y + q.y + b1v.y;
      float tz = p.z + q.z + b1v.z, tw = p.w + q.w + b1v.w;
      tx = fmaf(ev.x, w0.x, fmaf(ev.y, w1.x, fmaf(ev.z, w2.x, fmaf(ev.w, w3.x, tx))));
      ty = fmaf(ev.x, w0.y, fmaf(ev.y, w1.y, fmaf(ev.z, w2.y, fmaf(ev.w, w3.y, ty))));
      tz = fmaf(ev.x, w0.z, fmaf(ev.y, w1.z, fmaf(ev.z, w2.z, fmaf(ev.w, w3.z, tz))));
      tw = fmaf(ev.x, w0.w, fmaf(ev.y, w1.w, fmaf(ev.z, w2.w, fmaf(ev.w, w3.w, tw))));
      tb = make_ushort4(f2b(fmaxf(tx, 0.f)), f2b(fmaxf(ty, 0.f)),
                        f2b(fmaxf(tz, 0.f)), f2b(fmaxf(tw, 0.f)));
    }
    *(ushort4*)&Tl[el * TS + d0] = tb;
  }
  __syncthreads();  // T tile complete

  // ---- Phase B: MFMA ----
  floatx4 acc[4][2];
#pragma unroll
  for (int mt = 0; mt < 4; ++mt) {
    acc[mt][0] = (floatx4)(0.0f);
    acc[mt][1] = (floatx4)(0.0f);
  }
#pragma unroll
  for (int mt = 0; mt < 4; ++mt) {
    const __bf16* ar = (const __bf16*)Tl + (16 * mt + m16) * TS + quad * 8;
    bf16x8 a0 = *(const bf16x8*)(ar + 0);
    bf16x8 a1 = *(const bf16x8*)(ar + 32);
    bf16x8 a2 = *(const bf16x8*)(ar + 64);
    bf16x8 a3 = *(const bf16x8*)(ar + 96);
    acc[mt][0] = __builtin_amdgcn_mfma_f32_16x16x32_bf16(a0, bB[0][0], acc[mt][0], 0, 0, 0);
    acc[mt][1] = __builtin_amdgcn_mfma_f32_16x16x32_bf16(a0, bB[1][0], acc[mt][1], 0, 0, 0);
    acc[mt][0] = __builtin_amdgcn_mfma_f32_16x16x32_bf16(a1, bB[0][1], acc[mt][0], 0, 0, 0);
    acc[mt][1] = __builtin_amdgcn_mfma_f32_16x16x32_bf16(a1, bB[1][1], acc[mt][1], 0, 0, 0);
    acc[mt][0] = __builtin_amdgcn_mfma_f32_16x16x32_bf16(a2, bB[0][2], acc[mt][0], 0, 0, 0);
    acc[mt][1] = __builtin_amdgcn_mfma_f32_16x16x32_bf16(a2, bB[1][2], acc[mt][1], 0, 0, 0);
    acc[mt][0] = __builtin_amdgcn_mfma_f32_16x16x32_bf16(a3, bB[0][3], acc[mt][0], 0, 0, 0);
    acc[mt][1] = __builtin_amdgcn_mfma_f32_16x16x32_bf16(a3, bB[1][3], acc[mt][1], 0, 0, 0);
  }

  // epilogue: relu(acc + b2f) -> Ms (fp32)
  float bv0 = B2f[32 * wv + m16];
  float bv1 = B2f[32 * wv + 16 + m16];
#pragma unroll
  for (int mt = 0; mt < 4; ++mt) {
#pragma unroll
    for (int ntl = 0; ntl < 2; ++ntl) {
      int col = 32 * wv + 16 * ntl + m16;
      float bv = ntl ? bv1 : bv0;
#pragma unroll
      for (int reg = 0; reg < 4; ++reg) {
        int row = 16 * mt + quad * 4 + reg;
        Ms[row * MSS + col] = fmaxf(acc[mt][ntl][reg] + bv, 0.f);
      }
    }
  }
  __syncthreads();  // Ms complete

  // ---- Phase C: segmented reduce over equal-dst runs ----
  const int d = tid & 127, half = tid >> 7;
  const int dfirst = sdst[0], dlast = sdst[63];
  for (int s = half; s < 64; s += 2) {
    int dn = sdst[s];
    if (dn < 0) continue;
    if (s > 0 && sdst[s - 1] == dn) continue;  // not a segment start
    float sum = 0.f;
    int e = s;
    do { sum += Ms[e * MSS + d]; ++e; } while (e < 64 && sdst[e] == dn);
    float* ap = aggr + (size_t)dn * 128 + d;
    if (dn == dfirst || dn == dlast) atomicAdd(ap, sum);
    else *ap = sum;  // all edges of dn are inside this tile
  }
}

// ---------------- pooling ----------------
__global__ __launch_bounds__(128) void pool_sum_kernel(
    const float* __restrict__ h, const int* __restrict__ batch,
    float* __restrict__ sums, int* __restrict__ gcnt, int Nn) {
  int n0 = blockIdx.x * 256;
  if (n0 >= Nn) return;
  int nend = min(n0 + 256, Nn);
  int d = threadIdx.x;
  int gcur = batch[n0];
  float run = 0.f;
  int cnt = 0;
  for (int n = n0; n < nend; ++n) {
    int g = batch[n];
    if (g != gcur) {
      atomicAdd(&sums[(size_t)gcur * 128 + d], run);
      if (d == 0) atomicAdd(&gcnt[gcur], cnt);
      run = 0.f; cnt = 0; gcur = g;
    }
    run += h[(size_t)n * 128 + d];
    cnt += 1;
  }
  atomicAdd(&sums[(size_t)gcur * 128 + d], run);
  if (d == 0) atomicAdd(&gcnt[gcur], cnt);
}

__global__ __launch_bounds__(128) void pred_kernel(
    const float* __restrict__ sums, const int* __restrict__ gcnt,
    const float* __restrict__ pw, const float* __restrict__ pb, float* __restrict__ out) {
  __shared__ float red[2];
  int g = blockIdx.x, d = threadIdx.x;
  float c = fmaxf((float)gcnt[g], 1.f);
  float v = (sums[(size_t)g * 128 + d] / c) * pw[d];
  for (int o = 32; o > 0; o >>= 1) v += __shfl_down(v, o, 64);
  if ((d & 63) == 0) red[d >> 6] = v;
  __syncthreads();
  if (d == 0) out[g] = red[0] + red[1] + pb[0];
}

// ---------------- launch ----------------
extern "C" void kernel_launch(void* const* d_in, const int* in_sizes, int n_in,
                              void* d_out, int out_size, void* d_ws, size_t ws_size,
                              hipStream_t stream) {
  const float* x = (const float*)d_in[0];
  const float* pos = (const float*)d_in[1];
  const int* ei = (const int*)d_in[2];
  const float* ea = (const float*)d_in[3];
  const int* batch = (const int*)d_in[4];
  const float* lin_w = (const float*)d_in[5];
  const float* lin_b = (const float*)d_in[6];
  const float* mw1 = (const float*)d_in[7];
  const float* mb1 = (const float*)d_in[8];
  const float* mg = (const float*)d_in[9];
  const float* mbb = (const float*)d_in[10];
  const float* mm = (const float*)d_in[11];
  const float* mv = (const float*)d_in[12];
  const float* mw2 = (const float*)d_in[13];
  const float* mb2 = (const float*)d_in[14];
  const float* uw1 = (const float*)d_in[15];
  const float* ub1 = (const float*)d_in[16];
  const float* ug = (const float*)d_in[17];
  const float* ubb = (const float*)d_in[18];
  const float* um = (const float*)d_in[19];
  const float* uv = (const float*)d_in[20];
  const float* uw2 = (const float*)d_in[21];
  const float* ub2 = (const float*)d_in[22];
  const float* pw = (const float*)d_in[23];
  const float* pb = (const float*)d_in[24];
  float* out = (float*)d_out;

  const int Nn = in_sizes[0] / 11;
  const int Ee = in_sizes[3] / 4;
  const int* srcp = ei;        // edge_index[0] = source j
  const int* dstp = ei + Ee;   // edge_index[1] = target i

  char* wsb = (char*)d_ws;
  size_t off = 0;
  auto alloc = [&](size_t bytes) -> void* {
    void* p = wsb + off;
    off = (off + bytes + 255) & ~(size_t)255;
    return p;
  };
  float* h = (float*)alloc((size_t)Nn * 128 * 4);
  float* Pb = (float*)alloc((size_t)Nn * 128 * 4);
  float* Qb = (float*)alloc((size_t)Nn * 128 * 4);
  float* aggr = (float*)alloc((size_t)Nn * 128 * 4);
  int* dst_s = (int*)alloc((size_t)Ee * 4);
  int* src_s = (int*)alloc((size_t)Ee * 4);
  float* ea_s = (float*)alloc((size_t)Ee * 16);
  int* count = (int*)alloc((size_t)Nn * 4);
  int* cursor = (int*)alloc((size_t)Nn * 4);
  unsigned short* mW2fT = (unsigned short*)alloc((size_t)4 * 128 * 128 * 2);
  float* mB2f = (float*)alloc((size_t)4 * 128 * 4);
  float* uW2f = (float*)alloc((size_t)4 * 128 * 128 * 4);
  float* uB2f = (float*)alloc((size_t)4 * 128 * 4);
  float* sums = (float*)alloc((size_t)out_size * 128 * 4);
  int* gcnt = (int*)alloc((size_t)out_size * 4);
  (void)ws_size; (void)n_in;

  fold_kernel<<<8, 128, 0, stream>>>(mw2, mb2, mg, mbb, mm, mv,
                                     uw2, ub2, ug, ubb, um, uv,
                                     mB2f, mW2fT, uW2f, uB2f);
  lin_in_kernel<<<(Nn * 128 + 255) / 256, 256, 0, stream>>>(x, pos, lin_w, lin_b, h, Nn);

  hipMemsetAsync(count, 0, (size_t)Nn * 4, stream);
  hist_kernel<<<(Ee + 255) / 256, 256, 0, stream>>>(dstp, count, Ee);
  scan_kernel<<<1, 1024, 0, stream>>>(count, cursor, Nn);
  scatter_kernel<<<(Ee + 255) / 256, 256, 0, stream>>>(srcp, dstp, ea, cursor,
                                                       dst_s, src_s, ea_s, Ee);

  const int gblocks = (Nn + 63) / 64;
  for (int l = 0; l < 4; ++l) {
    const float* W1 = mw1 + (size_t)l * 260 * 128;
    gemm128<<<gblocks, 256, 0, stream>>>(h, W1, nullptr, Pb, Nn, 0);                 // P = h@W1a
    gemm128<<<gblocks, 256, 0, stream>>>(h, W1 + 128 * 128, nullptr, Qb, Nn, 0);     // Q = h@W1b
    hipMemsetAsync(aggr, 0, (size_t)Nn * 128 * 4, stream);
    edge_kernel<<<(Ee + 63) / 64, 256, 0, stream>>>(Pb, Qb, ea_s, dst_s, src_s,
                                                    W1 + 256 * 128, mb1 + l * 128,
                                                    mW2fT + (size_t)l * 16384, mB2f + l * 128,
                                                    aggr, Ee);
    const float* U1 = uw1 + (size_t)l * 256 * 128;
    gemm128<<<gblocks, 256, 0, stream>>>(h, U1, ub1 + l * 128, Pb, Nn, 0);           // tmp = h@U1a + ub1
    gemm128<<<gblocks, 256, 0, stream>>>(aggr, U1 + 128 * 128, nullptr, Pb, Nn, 1);  // tmp = relu(tmp + aggr@U1b)
    gemm128<<<gblocks, 256, 0, stream>>>(Pb, uW2f + (size_t)l * 16384, uB2f + l * 128, h, Nn, 2); // h += relu(...)
  }

  hipMemsetAsync(sums, 0, (size_t)out_size * 128 * 4, stream);
  hipMemsetAsync(gcnt, 0, (size_t)out_size * 4, stream);
  pool_sum_kernel<<<(Nn + 255) / 256, 128, 0, stream>>>(h, batch, sums, gcnt, Nn);
  pred_kernel<<<out_size, 128, 0, stream>>>(sums, gcnt, pw, pb, out);
}

// Round 3
// 2459.812 us; speedup vs baseline: 2.7153x; 1.5828x over previous
//
#include <hip/hip_runtime.h>
#include <hip/hip_bf16.h>

// MPNN: N=100000 nodes, E=1600000 edges, D=128, L=4, G=64.
// All GEMM-shaped work on MFMA bf16 (fp32 accumulate), fp32 residual stream h.
//   prep: fold BN into W2 (both MLPs), transpose all B-matrices to [n][k] bf16.
//   h = cat(x,pos)@Win + bin                                   (fp32)
//   per layer:
//     pq_kernel:  P = h@W1a, Q = h@W1b   -> bf16 [N][128] each (MFMA)
//     edge_kernel: t = relu(P[dst]+Q[src]+ea@W1c+b1) -> bf16 LDS
//                  m = relu(t@W2f+b2f)   (MFMA, W frags from global)
//                  segmented reduce over dst-sorted runs -> aggr fp32
//     upd_kernel: u1 = relu([h|aggr]@U1+ub1) (MFMA K=256) -> bf16 LDS
//                  h += relu(u1@U2f+uB2f)    (MFMA K=128), in-place
//   pool: segment mean over sorted batch, then @pred_w + pred_b.
// MFMA operand swap: acc = mfma(Wfrag, actFrag, acc) gives D[n][m] so each
// lane holds (row = lane&15 local, 4 consecutive cols = quad*4+reg) ->
// row-major ushort4/float4 epilogue stores.

#define EPSBN 1e-5f
#define TS 136   // bf16 elems per LDS row for 128-wide tiles (272 B = 17*16 B)
#define AS 264   // bf16 elems per LDS row for 256-wide tiles (528 B = 33*16 B)

typedef __bf16 bf16x8 __attribute__((ext_vector_type(8)));
typedef float floatx4 __attribute__((ext_vector_type(4)));

static __device__ __forceinline__ unsigned short f2b(float f) {
  union { float f; unsigned u; } v; v.f = f;
  unsigned u = v.u;
  return (unsigned short)((u + 0x7fffu + ((u >> 16) & 1u)) >> 16);  // RNE
}
static __device__ __forceinline__ float ubits(unsigned u) {
  union { unsigned u; float f; } v; v.u = u; return v.f;
}
static __device__ __forceinline__ float b2f(unsigned short s) {
  return ubits((unsigned)s << 16);
}

// ---------------- fold BN into second linear, write transposed bf16 ----------------
__global__ __launch_bounds__(128) void fold_kernel(
    const float* __restrict__ mw2, const float* __restrict__ mb2,
    const float* __restrict__ mg, const float* __restrict__ mb,
    const float* __restrict__ mm, const float* __restrict__ mv,
    const float* __restrict__ uw2, const float* __restrict__ ub2,
    const float* __restrict__ ug, const float* __restrict__ ub,
    const float* __restrict__ um, const float* __restrict__ uv,
    unsigned short* __restrict__ mW2fT, float* __restrict__ mB2f,
    unsigned short* __restrict__ uW2fT, float* __restrict__ uB2f) {
  int l = blockIdx.x & 3;
  bool isu = blockIdx.x >= 4;
  const float* W2 = (isu ? uw2 : mw2) + (size_t)l * 128 * 128;
  const float* b2 = (isu ? ub2 : mb2) + l * 128;
  const float* gg = (isu ? ug : mg) + l * 128;
  const float* bb = (isu ? ub : mb) + l * 128;
  const float* mn = (isu ? um : mm) + l * 128;
  const float* vr = (isu ? uv : mv) + l * 128;
  unsigned short* WfT = (isu ? uW2fT : mW2fT) + (size_t)l * 128 * 128;
  float* Bf = (isu ? uB2f : mB2f) + l * 128;
  __shared__ float a[128], c[128];
  int d = threadIdx.x;
  float ad = gg[d] * rsqrtf(vr[d] + EPSBN);
  a[d] = ad;
  c[d] = bb[d] - mn[d] * ad;
  __syncthreads();
  float acc = b2[d];
  for (int k = 0; k < 128; ++k) {
    float w = W2[k * 128 + d];
    WfT[(size_t)d * 128 + k] = f2b(a[k] * w);  // [n][k] bf16
    acc = fmaf(c[k], w, acc);
  }
  Bf[d] = acc;
}

// ---------------- transpose W1ab / U1 to [n][k] bf16 ----------------
__global__ __launch_bounds__(256) void transp_kernel(
    const float* __restrict__ mw1, const float* __restrict__ uw1,
    unsigned short* __restrict__ W1abT, unsigned short* __restrict__ U1T) {
  int l = blockIdx.x & 3;
  bool isu = blockIdx.x >= 4;
  int tid = threadIdx.x;
  if (!isu) {
    const float* W = mw1 + (size_t)l * 260 * 128;
    unsigned short* T = W1abT + (size_t)l * 256 * 128;
    for (int i = tid; i < 256 * 128; i += 256) {
      int n = i >> 7, k = i & 127;
      float v = (n < 128) ? W[(size_t)k * 128 + n] : W[(size_t)(128 + k) * 128 + (n - 128)];
      T[i] = f2b(v);
    }
  } else {
    const float* W = uw1 + (size_t)l * 256 * 128;
    unsigned short* T = U1T + (size_t)l * 128 * 256;
    for (int i = tid; i < 128 * 256; i += 256) {
      int n = i >> 8, k = i & 255;
      T[i] = f2b(W[(size_t)k * 128 + n]);
    }
  }
}

// ---------------- input projection ----------------
__global__ __launch_bounds__(256) void lin_in_kernel(
    const float* __restrict__ x, const float* __restrict__ pos,
    const float* __restrict__ W, const float* __restrict__ b,
    float* __restrict__ h, int Nn) {
  int gi = blockIdx.x * 256 + threadIdx.x;
  if (gi >= Nn * 128) return;
  int n = gi >> 7, d = gi & 127;
  float acc = b[d];
#pragma unroll
  for (int j = 0; j < 11; ++j) acc = fmaf(x[(size_t)n * 11 + j], W[j * 128 + d], acc);
#pragma unroll
  for (int j = 0; j < 3; ++j) acc = fmaf(pos[(size_t)n * 3 + j], W[(11 + j) * 128 + d], acc);
  h[gi] = acc;
}

// ---------------- counting sort of edges by dst ----------------
__global__ __launch_bounds__(256) void hist_kernel(const int* __restrict__ dst, int* __restrict__ count, int Ee) {
  int i = blockIdx.x * 256 + threadIdx.x;
  if (i < Ee) atomicAdd(&count[dst[i]], 1);
}

__global__ __launch_bounds__(1024) void scan_kernel(const int* __restrict__ count, int* __restrict__ cursor, int n) {
  __shared__ int buf[1024];
  __shared__ int carry;
  if (threadIdx.x == 0) carry = 0;
  __syncthreads();
  for (int base = 0; base < n; base += 1024) {
    int i = base + threadIdx.x;
    int v = (i < n) ? count[i] : 0;
    buf[threadIdx.x] = v;
    __syncthreads();
    for (int off = 1; off < 1024; off <<= 1) {
      int t = (threadIdx.x >= off) ? buf[threadIdx.x - off] : 0;
      __syncthreads();
      buf[threadIdx.x] += t;
      __syncthreads();
    }
    int incl = buf[threadIdx.x];
    if (i < n) cursor[i] = carry + incl - v;  // exclusive
    __syncthreads();
    if (threadIdx.x == 1023) carry += buf[1023];
    __syncthreads();
  }
}

__global__ __launch_bounds__(256) void scatter_kernel(
    const int* __restrict__ src, const int* __restrict__ dst, const float* __restrict__ ea,
    int* __restrict__ cursor, int* __restrict__ dst_s, int* __restrict__ src_s,
    float* __restrict__ ea_s, int Ee) {
  int e = blockIdx.x * 256 + threadIdx.x;
  if (e >= Ee) return;
  int dn = dst[e];
  int pos = atomicAdd(&cursor[dn], 1);
  dst_s[pos] = dn;
  src_s[pos] = src[e];
  *(float4*)(ea_s + (size_t)pos * 4) = *(const float4*)(ea + (size_t)e * 4);
}

// ---------------- pq_kernel: P = h@W1a, Q = h@W1b (bf16 out, MFMA) ----------------
__global__ __launch_bounds__(256) void pq_kernel(
    const float* __restrict__ h, const unsigned short* __restrict__ W1abT,
    unsigned short* __restrict__ P, unsigned short* __restrict__ Q, int Nn) {
  __shared__ unsigned short hs[64 * TS];
  const int tid = threadIdx.x;
  const int row0 = blockIdx.x * 64;
  // stage h tile fp32 -> bf16 LDS
#pragma unroll
  for (int i = 0; i < 8; ++i) {
    int idx = tid + i * 256;
    int r = idx >> 5, c4 = (idx & 31) << 2;
    float4 v = make_float4(0.f, 0.f, 0.f, 0.f);
    if (row0 + r < Nn) v = *(const float4*)(h + (size_t)(row0 + r) * 128 + c4);
    ushort4 o = make_ushort4(f2b(v.x), f2b(v.y), f2b(v.z), f2b(v.w));
    *(ushort4*)&hs[r * TS + c4] = o;
  }
  __syncthreads();
  const int lane = tid & 63, wv = tid >> 6;
  const int m16 = lane & 15, quad = lane >> 4;
  floatx4 acc[4][4];  // [mt][nt]
#pragma unroll
  for (int mt = 0; mt < 4; ++mt)
#pragma unroll
    for (int nt = 0; nt < 4; ++nt) acc[mt][nt] = (floatx4)(0.0f);
  const __bf16* WT = (const __bf16*)W1abT;
  const __bf16* TlB = (const __bf16*)hs;
#pragma unroll
  for (int kb = 0; kb < 4; ++kb) {
    bf16x8 a[4], w[4];
#pragma unroll
    for (int mt = 0; mt < 4; ++mt)
      a[mt] = *(const bf16x8*)(TlB + (16 * mt + m16) * TS + kb * 32 + quad * 8);
#pragma unroll
    for (int nt = 0; nt < 4; ++nt)
      w[nt] = *(const bf16x8*)(WT + (size_t)(64 * wv + 16 * nt + m16) * 128 + kb * 32 + quad * 8);
#pragma unroll
    for (int mt = 0; mt < 4; ++mt)
#pragma unroll
      for (int nt = 0; nt < 4; ++nt)
        acc[mt][nt] = __builtin_amdgcn_mfma_f32_16x16x32_bf16(w[nt], a[mt], acc[mt][nt], 0, 0, 0);
  }
  // epilogue: lane holds row = row0+16mt+m16, cols n0..n0+3
#pragma unroll
  for (int mt = 0; mt < 4; ++mt) {
    int row = row0 + 16 * mt + m16;
    if (row >= Nn) continue;
#pragma unroll
    for (int nt = 0; nt < 4; ++nt) {
      int n0 = 64 * wv + 16 * nt + 4 * quad;
      floatx4 A = acc[mt][nt];
      ushort4 o = make_ushort4(f2b(A[0]), f2b(A[1]), f2b(A[2]), f2b(A[3]));
      if (n0 < 128) *(ushort4*)(P + (size_t)row * 128 + n0) = o;
      else *(ushort4*)(Q + (size_t)row * 128 + (n0 - 128)) = o;
    }
  }
}

// ---------------- edge message kernel (MFMA bf16, bf16 P/Q gathers) ----------------
__global__ __launch_bounds__(256) void edge_kernel(
    const unsigned short* __restrict__ P, const unsigned short* __restrict__ Q,
    const float* __restrict__ ea_s, const int* __restrict__ dst_s, const int* __restrict__ src_s,
    const float* __restrict__ W1c, const float* __restrict__ b1,
    const unsigned short* __restrict__ W2fT, const float* __restrict__ B2f,
    float* __restrict__ aggr, int Ee) {
  __shared__ unsigned short Tl[64 * TS];
  __shared__ unsigned short Msb[64 * TS];
  __shared__ float sea[64 * 4];
  __shared__ int sdst[64], ssrc[64];
  const int tid = threadIdx.x;
  const int e0 = blockIdx.x * 64;
  if (tid < 64) {
    int e = e0 + tid;
    bool ok = e < Ee;
    sdst[tid] = ok ? dst_s[e] : -1;
    ssrc[tid] = ok ? src_s[e] : 0;
    float4 ev = ok ? *(const float4*)(ea_s + (size_t)e * 4) : make_float4(0.f, 0.f, 0.f, 0.f);
    *(float4*)&sea[tid * 4] = ev;
  }
  // per-thread W1c slice: cols c0..c0+7
  const int rw = tid >> 4, c0 = (tid & 15) << 3;
  float wc[4][8], b1r[8];
#pragma unroll
  for (int r = 0; r < 4; ++r)
#pragma unroll
    for (int j = 0; j < 8; ++j) wc[r][j] = W1c[r * 128 + c0 + j];
#pragma unroll
  for (int j = 0; j < 8; ++j) b1r[j] = b1[c0 + j];
  __syncthreads();

  // ---- Phase A: t = relu(P[dst]+Q[src]+ea@W1c+b1) -> bf16 Tl ----
#pragma unroll
  for (int p = 0; p < 4; ++p) {
    int row = 16 * p + rw;
    int dn = sdst[row];
    uint4 out = make_uint4(0u, 0u, 0u, 0u);
    if (dn >= 0) {
      int sn = ssrc[row];
      uint4 pv = *(const uint4*)(P + (size_t)dn * 128 + c0);
      uint4 qv = *(const uint4*)(Q + (size_t)sn * 128 + c0);
      float e0f = sea[row * 4 + 0], e1f = sea[row * 4 + 1];
      float e2f = sea[row * 4 + 2], e3f = sea[row * 4 + 3];
      unsigned pu[4] = {pv.x, pv.y, pv.z, pv.w};
      unsigned qu[4] = {qv.x, qv.y, qv.z, qv.w};
      unsigned ou[4];
#pragma unroll
      for (int g = 0; g < 4; ++g) {
        float plo = ubits(pu[g] << 16), phi = ubits(pu[g] & 0xffff0000u);
        float qlo = ubits(qu[g] << 16), qhi = ubits(qu[g] & 0xffff0000u);
        int j0 = 2 * g, j1 = 2 * g + 1;
        float t0 = plo + qlo + b1r[j0];
        float t1 = phi + qhi + b1r[j1];
        t0 = fmaf(e0f, wc[0][j0], fmaf(e1f, wc[1][j0], fmaf(e2f, wc[2][j0], fmaf(e3f, wc[3][j0], t0))));
        t1 = fmaf(e0f, wc[0][j1], fmaf(e1f, wc[1][j1], fmaf(e2f, wc[2][j1], fmaf(e3f, wc[3][j1], t1))));
        unsigned lo = f2b(fmaxf(t0, 0.f));
        unsigned hi = f2b(fmaxf(t1, 0.f));
        ou[g] = lo | (hi << 16);
      }
      out = make_uint4(ou[0], ou[1], ou[2], ou[3]);
    }
    *(uint4*)&Tl[row * TS + c0] = out;
  }
  __syncthreads();

  // ---- Phase B: m = T @ W2f (operand-swapped MFMA) ----
  const int lane = tid & 63, wv = tid >> 6;
  const int m16 = lane & 15, quad = lane >> 4;
  floatx4 acc[4][2];
#pragma unroll
  for (int mt = 0; mt < 4; ++mt) { acc[mt][0] = (floatx4)(0.0f); acc[mt][1] = (floatx4)(0.0f); }
  const __bf16* WT = (const __bf16*)W2fT;
  const __bf16* TlB = (const __bf16*)Tl;
#pragma unroll
  for (int kb = 0; kb < 4; ++kb) {
    bf16x8 w0 = *(const bf16x8*)(WT + (size_t)(32 * wv + m16) * 128 + kb * 32 + quad * 8);
    bf16x8 w1 = *(const bf16x8*)(WT + (size_t)(32 * wv + 16 + m16) * 128 + kb * 32 + quad * 8);
    bf16x8 a[4];
#pragma unroll
    for (int mt = 0; mt < 4; ++mt)
      a[mt] = *(const bf16x8*)(TlB + (16 * mt + m16) * TS + kb * 32 + quad * 8);
#pragma unroll
    for (int mt = 0; mt < 4; ++mt) {
      acc[mt][0] = __builtin_amdgcn_mfma_f32_16x16x32_bf16(w0, a[mt], acc[mt][0], 0, 0, 0);
      acc[mt][1] = __builtin_amdgcn_mfma_f32_16x16x32_bf16(w1, a[mt], acc[mt][1], 0, 0, 0);
    }
  }
  // epilogue: relu(acc + b2f) -> bf16 Msb (lane holds row, 4 consecutive cols)
  {
    int n0 = 32 * wv + 4 * quad;
    float4 bv0 = *(const float4*)(B2f + n0);
    float4 bv1 = *(const float4*)(B2f + n0 + 16);
#pragma unroll
    for (int mt = 0; mt < 4; ++mt) {
      int row = 16 * mt + m16;
      floatx4 A0 = acc[mt][0], A1 = acc[mt][1];
      ushort4 o0 = make_ushort4(f2b(fmaxf(A0[0] + bv0.x, 0.f)), f2b(fmaxf(A0[1] + bv0.y, 0.f)),
                                f2b(fmaxf(A0[2] + bv0.z, 0.f)), f2b(fmaxf(A0[3] + bv0.w, 0.f)));
      ushort4 o1 = make_ushort4(f2b(fmaxf(A1[0] + bv1.x, 0.f)), f2b(fmaxf(A1[1] + bv1.y, 0.f)),
                                f2b(fmaxf(A1[2] + bv1.z, 0.f)), f2b(fmaxf(A1[3] + bv1.w, 0.f)));
      *(ushort4*)&Msb[row * TS + n0] = o0;
      *(ushort4*)&Msb[row * TS + n0 + 16] = o1;
    }
  }
  __syncthreads();

  // ---- Phase C: segmented reduce over equal-dst runs ----
  const int d = tid & 127, half = tid >> 7;
  const int dfirst = sdst[0], dlast = sdst[63];
  for (int s = half; s < 64; s += 2) {
    int dn = sdst[s];
    if (dn < 0) continue;
    if (s > 0 && sdst[s - 1] == dn) continue;  // not a segment start
    float sum = 0.f;
    int e = s;
    do { sum += b2f(Msb[e * TS + d]); ++e; } while (e < 64 && sdst[e] == dn);
    float* ap = aggr + (size_t)dn * 128 + d;
    if (dn == dfirst || dn == dlast) atomicAdd(ap, sum);
    else *ap = sum;  // all edges of dn are inside this tile
  }
}

// ---------------- fused update MLP (MFMA, in-place h) ----------------
__global__ __launch_bounds__(256) void upd_kernel(
    float* __restrict__ h, const float* __restrict__ aggr,
    const unsigned short* __restrict__ U1T, const float* __restrict__ ub1,
    const unsigned short* __restrict__ uW2fT, const float* __restrict__ uB2f, int Nn) {
  __shared__ unsigned short as_[64 * AS];
  __shared__ unsigned short u1s[64 * TS];
  const int tid = threadIdx.x;
  const int row0 = blockIdx.x * 64;
  // stage [h | aggr] -> bf16 LDS (K=256)
#pragma unroll
  for (int i = 0; i < 8; ++i) {
    int idx = tid + i * 256;
    int r = idx >> 5, c4 = (idx & 31) << 2;
    float4 v = make_float4(0.f, 0.f, 0.f, 0.f);
    if (row0 + r < Nn) v = *(const float4*)(h + (size_t)(row0 + r) * 128 + c4);
    *(ushort4*)&as_[r * AS + c4] = make_ushort4(f2b(v.x), f2b(v.y), f2b(v.z), f2b(v.w));
  }
#pragma unroll
  for (int i = 0; i < 8; ++i) {
    int idx = tid + i * 256;
    int r = idx >> 5, c4 = (idx & 31) << 2;
    float4 v = make_float4(0.f, 0.f, 0.f, 0.f);
    if (row0 + r < Nn) v = *(const float4*)(aggr + (size_t)(row0 + r) * 128 + c4);
    *(ushort4*)&as_[r * AS + 128 + c4] = make_ushort4(f2b(v.x), f2b(v.y), f2b(v.z), f2b(v.w));
  }
  __syncthreads();
  const int lane = tid & 63, wv = tid >> 6;
  const int m16 = lane & 15, quad = lane >> 4;
  const __bf16* asB = (const __bf16*)as_;
  // pass 1: u1 = relu([h|aggr]@U1 + ub1), K=256
  {
    floatx4 acc[4][2];
#pragma unroll
    for (int mt = 0; mt < 4; ++mt) { acc[mt][0] = (floatx4)(0.0f); acc[mt][1] = (floatx4)(0.0f); }
    const __bf16* WT = (const __bf16*)U1T;
#pragma unroll
    for (int kb = 0; kb < 8; ++kb) {
      bf16x8 w0 = *(const bf16x8*)(WT + (size_t)(32 * wv + m16) * 256 + kb * 32 + quad * 8);
      bf16x8 w1 = *(const bf16x8*)(WT + (size_t)(32 * wv + 16 + m16) * 256 + kb * 32 + quad * 8);
      bf16x8 a[4];
#pragma unroll
      for (int mt = 0; mt < 4; ++mt)
        a[mt] = *(const bf16x8*)(asB + (16 * mt + m16) * AS + kb * 32 + quad * 8);
#pragma unroll
      for (int mt = 0; mt < 4; ++mt) {
        acc[mt][0] = __builtin_amdgcn_mfma_f32_16x16x32_bf16(w0, a[mt], acc[mt][0], 0, 0, 0);
        acc[mt][1] = __builtin_amdgcn_mfma_f32_16x16x32_bf16(w1, a[mt], acc[mt][1], 0, 0, 0);
      }
    }
    int n0 = 32 * wv + 4 * quad;
    float4 bv0 = *(const float4*)(ub1 + n0);
    float4 bv1 = *(const float4*)(ub1 + n0 + 16);
#pragma unroll
    for (int mt = 0; mt < 4; ++mt) {
      int row = 16 * mt + m16;
      floatx4 A0 = acc[mt][0], A1 = acc[mt][1];
      *(ushort4*)&u1s[row * TS + n0] =
          make_ushort4(f2b(fmaxf(A0[0] + bv0.x, 0.f)), f2b(fmaxf(A0[1] + bv0.y, 0.f)),
                       f2b(fmaxf(A0[2] + bv0.z, 0.f)), f2b(fmaxf(A0[3] + bv0.w, 0.f)));
      *(ushort4*)&u1s[row * TS + n0 + 16] =
          make_ushort4(f2b(fmaxf(A1[0] + bv1.x, 0.f)), f2b(fmaxf(A1[1] + bv1.y, 0.f)),
                       f2b(fmaxf(A1[2] + bv1.z, 0.f)), f2b(fmaxf(A1[3] + bv1.w, 0.f)));
    }
  }
  __syncthreads();
  // pass 2: h += relu(u1@U2f + uB2f), K=128
  {
    floatx4 acc[4][2];
#pragma unroll
    for (int mt = 0; mt < 4; ++mt) { acc[mt][0] = (floatx4)(0.0f); acc[mt][1] = (floatx4)(0.0f); }
    const __bf16* WT = (const __bf16*)uW2fT;
    const __bf16* u1B = (const __bf16*)u1s;
#pragma unroll
    for (int kb = 0; kb < 4; ++kb) {
      bf16x8 w0 = *(const bf16x8*)(WT + (size_t)(32 * wv + m16) * 128 + kb * 32 + quad * 8);
      bf16x8 w1 = *(const bf16x8*)(WT + (size_t)(32 * wv + 16 + m16) * 128 + kb * 32 + quad * 8);
      bf16x8 a[4];
#pragma unroll
      for (int mt = 0; mt < 4; ++mt)
        a[mt] = *(const bf16x8*)(u1B + (16 * mt + m16) * TS + kb * 32 + quad * 8);
#pragma unroll
      for (int mt = 0; mt < 4; ++mt) {
        acc[mt][0] = __builtin_amdgcn_mfma_f32_16x16x32_bf16(w0, a[mt], acc[mt][0], 0, 0, 0);
        acc[mt][1] = __builtin_amdgcn_mfma_f32_16x16x32_bf16(w1, a[mt], acc[mt][1], 0, 0, 0);
      }
    }
    int n0 = 32 * wv + 4 * quad;
    float4 bv0 = *(const float4*)(uB2f + n0);
    float4 bv1 = *(const float4*)(uB2f + n0 + 16);
#pragma unroll
    for (int mt = 0; mt < 4; ++mt) {
      int row = row0 + 16 * mt + m16;
      if (row >= Nn) continue;
      floatx4 A0 = acc[mt][0], A1 = acc[mt][1];
      float* hp0 = h + (size_t)row * 128 + n0;
      float4 hv0 = *(float4*)hp0;
      *(float4*)hp0 = make_float4(hv0.x + fmaxf(A0[0] + bv0.x, 0.f), hv0.y + fmaxf(A0[1] + bv0.y, 0.f),
                                  hv0.z + fmaxf(A0[2] + bv0.z, 0.f), hv0.w + fmaxf(A0[3] + bv0.w, 0.f));
      float* hp1 = hp0 + 16;
      float4 hv1 = *(float4*)hp1;
      *(float4*)hp1 = make_float4(hv1.x + fmaxf(A1[0] + bv1.x, 0.f), hv1.y + fmaxf(A1[1] + bv1.y, 0.f),
                                  hv1.z + fmaxf(A1[2] + bv1.z, 0.f), hv1.w + fmaxf(A1[3] + bv1.w, 0.f));
    }
  }
}

// ---------------- pooling ----------------
__global__ __launch_bounds__(128) void pool_sum_kernel(
    const float* __restrict__ h, const int* __restrict__ batch,
    float* __restrict__ sums, int* __restrict__ gcnt, int Nn) {
  int n0 = blockIdx.x * 256;
  if (n0 >= Nn) return;
  int nend = min(n0 + 256, Nn);
  int d = threadIdx.x;
  int gcur = batch[n0];
  float run = 0.f;
  int cnt = 0;
  for (int n = n0; n < nend; ++n) {
    int g = batch[n];
    if (g != gcur) {
      atomicAdd(&sums[(size_t)gcur * 128 + d], run);
      if (d == 0) atomicAdd(&gcnt[gcur], cnt);
      run = 0.f; cnt = 0; gcur = g;
    }
    run += h[(size_t)n * 128 + d];
    cnt += 1;
  }
  atomicAdd(&sums[(size_t)gcur * 128 + d], run);
  if (d == 0) atomicAdd(&gcnt[gcur], cnt);
}

__global__ __launch_bounds__(128) void pred_kernel(
    const float* __restrict__ sums, const int* __restrict__ gcnt,
    const float* __restrict__ pw, const float* __restrict__ pb, float* __restrict__ out) {
  __shared__ float red[2];
  int g = blockIdx.x, d = threadIdx.x;
  float c = fmaxf((float)gcnt[g], 1.f);
  float v = (sums[(size_t)g * 128 + d] / c) * pw[d];
  for (int o = 32; o > 0; o >>= 1) v += __shfl_down(v, o, 64);
  if ((d & 63) == 0) red[d >> 6] = v;
  __syncthreads();
  if (d == 0) out[g] = red[0] + red[1] + pb[0];
}

// ---------------- launch ----------------
extern "C" void kernel_launch(void* const* d_in, const int* in_sizes, int n_in,
                              void* d_out, int out_size, void* d_ws, size_t ws_size,
                              hipStream_t stream) {
  const float* x = (const float*)d_in[0];
  const float* pos = (const float*)d_in[1];
  const int* ei = (const int*)d_in[2];
  const float* ea = (const float*)d_in[3];
  const int* batch = (const int*)d_in[4];
  const float* lin_w = (const float*)d_in[5];
  const float* lin_b = (const float*)d_in[6];
  const float* mw1 = (const float*)d_in[7];
  const float* mb1 = (const float*)d_in[8];
  const float* mg = (const float*)d_in[9];
  const float* mbb = (const float*)d_in[10];
  const float* mm = (const float*)d_in[11];
  const float* mv = (const float*)d_in[12];
  const float* mw2 = (const float*)d_in[13];
  const float* mb2 = (const float*)d_in[14];
  const float* uw1 = (const float*)d_in[15];
  const float* ub1 = (const float*)d_in[16];
  const float* ug = (const float*)d_in[17];
  const float* ubb = (const float*)d_in[18];
  const float* um = (const float*)d_in[19];
  const float* uv = (const float*)d_in[20];
  const float* uw2 = (const float*)d_in[21];
  const float* ub2 = (const float*)d_in[22];
  const float* pw = (const float*)d_in[23];
  const float* pb = (const float*)d_in[24];
  float* out = (float*)d_out;

  const int Nn = in_sizes[0] / 11;
  const int Ee = in_sizes[3] / 4;
  const int* srcp = ei;        // edge_index[0] = source j
  const int* dstp = ei + Ee;   // edge_index[1] = target i

  char* wsb = (char*)d_ws;
  size_t off = 0;
  auto alloc = [&](size_t bytes) -> void* {
    void* p = wsb + off;
    off = (off + bytes + 255) & ~(size_t)255;
    return p;
  };
  float* h = (float*)alloc((size_t)Nn * 128 * 4);
  unsigned short* Pb = (unsigned short*)alloc((size_t)Nn * 128 * 2);
  unsigned short* Qb = (unsigned short*)alloc((size_t)Nn * 128 * 2);
  float* aggr = (float*)alloc((size_t)Nn * 128 * 4);
  int* dst_s = (int*)alloc((size_t)Ee * 4);
  int* src_s = (int*)alloc((size_t)Ee * 4);
  float* ea_s = (float*)alloc((size_t)Ee * 16);
  int* count = (int*)alloc((size_t)Nn * 4);
  int* cursor = (int*)alloc((size_t)Nn * 4);
  unsigned short* mW2fT = (unsigned short*)alloc((size_t)4 * 128 * 128 * 2);
  unsigned short* uW2fT = (unsigned short*)alloc((size_t)4 * 128 * 128 * 2);
  unsigned short* W1abT = (unsigned short*)alloc((size_t)4 * 256 * 128 * 2);
  unsigned short* U1T = (unsigned short*)alloc((size_t)4 * 128 * 256 * 2);
  float* mB2f = (float*)alloc((size_t)4 * 128 * 4);
  float* uB2f = (float*)alloc((size_t)4 * 128 * 4);
  float* sums = (float*)alloc((size_t)out_size * 128 * 4);
  int* gcnt = (int*)alloc((size_t)out_size * 4);
  (void)ws_size; (void)n_in;

  fold_kernel<<<8, 128, 0, stream>>>(mw2, mb2, mg, mbb, mm, mv,
                                     uw2, ub2, ug, ubb, um, uv,
                                     mW2fT, mB2f, uW2fT, uB2f);
  transp_kernel<<<8, 256, 0, stream>>>(mw1, uw1, W1abT, U1T);
  lin_in_kernel<<<(Nn * 128 + 255) / 256, 256, 0, stream>>>(x, pos, lin_w, lin_b, h, Nn);

  hipMemsetAsync(count, 0, (size_t)Nn * 4, stream);
  hist_kernel<<<(Ee + 255) / 256, 256, 0, stream>>>(dstp, count, Ee);
  scan_kernel<<<1, 1024, 0, stream>>>(count, cursor, Nn);
  scatter_kernel<<<(Ee + 255) / 256, 256, 0, stream>>>(srcp, dstp, ea, cursor,
                                                       dst_s, src_s, ea_s, Ee);

  const int gN = (Nn + 63) / 64;
  for (int l = 0; l < 4; ++l) {
    pq_kernel<<<gN, 256, 0, stream>>>(h, W1abT + (size_t)l * 256 * 128, Pb, Qb, Nn);
    hipMemsetAsync(aggr, 0, (size_t)Nn * 128 * 4, stream);
    edge_kernel<<<(Ee + 63) / 64, 256, 0, stream>>>(
        Pb, Qb, ea_s, dst_s, src_s,
        mw1 + (size_t)l * 260 * 128 + 256 * 128, mb1 + l * 128,
        mW2fT + (size_t)l * 16384, mB2f + l * 128, aggr, Ee);
    upd_kernel<<<gN, 256, 0, stream>>>(h, aggr,
                                       U1T + (size_t)l * 128 * 256, ub1 + l * 128,
                                       uW2fT + (size_t)l * 16384, uB2f + l * 128, Nn);
  }

  hipMemsetAsync(sums, 0, (size_t)out_size * 128 * 4, stream);
  hipMemsetAsync(gcnt, 0, (size_t)out_size * 4, stream);
  pool_sum_kernel<<<(Nn + 255) / 256, 128, 0, stream>>>(h, batch, sums, gcnt, Nn);
  pred_kernel<<<out_size, 128, 0, stream>>>(sums, gcnt, pw, pb, out);
}

// Round 4
// 2317.700 us; speedup vs baseline: 2.8818x; 1.0613x over previous
//
#include <hip/hip_runtime.h>
#include <hip/hip_bf16.h>

// MPNN: N=100000 nodes, E=1600000 edges, D=128, L=4, G=64.
// All GEMM-shaped work on MFMA bf16 (fp32 accumulate), fp32 residual stream h.
//   prep: fold BN into W2 (both MLPs), transpose all B-matrices to [n][k] bf16.
//   h = cat(x,pos)@Win + bin                                   (fp32)
//   per layer:
//     pq_kernel:  P = h@W1a, Q = h@W1b   -> bf16 [N][128] each (MFMA)
//     edge_kernel: t = relu(P[dst]+Q[src]+ea@W1c+b1) -> bf16 LDS (Tl)
//                  m = relu(t@W2f+b2f)   (MFMA) -> written back into Tl
//                  segmented reduce over dst-sorted runs -> aggr fp32
//     upd_kernel: u1 = relu([h|aggr]@U1+ub1) (MFMA K=256) -> bf16 LDS (overlaid)
//                  h += relu(u1@U2f+uB2f)    (MFMA K=128), in-place
//   pool: segment mean over sorted batch, then @pred_w + pred_b.
// MFMA operand swap: acc = mfma(Wfrag, actFrag, acc) gives D[n][m] so each
// lane holds (row = lane&15 local, 4 consecutive cols = quad*4+reg) ->
// row-major epilogue stores. bf16 packing via v_cvt_pk_bf16_f32.

#define EPSBN 1e-5f
#define TS 136   // bf16 elems per LDS row for 128-wide tiles (272 B = 17*16 B)
#define AS 264   // bf16 elems per LDS row for 256-wide tiles (528 B = 33*16 B)

typedef __bf16 bf16x8 __attribute__((ext_vector_type(8)));
typedef float floatx4 __attribute__((ext_vector_type(4)));

static __device__ __forceinline__ unsigned short f2b(float f) {
  union { float f; unsigned u; } v; v.f = f;
  unsigned u = v.u;
  return (unsigned short)((u + 0x7fffu + ((u >> 16) & 1u)) >> 16);  // RNE
}
static __device__ __forceinline__ unsigned pk2(float lo, float hi) {
  union { __hip_bfloat162 h; unsigned u; } v;
  v.h = __float22bfloat162_rn(make_float2(lo, hi));  // v_cvt_pk_bf16_f32
  return v.u;
}
static __device__ __forceinline__ float ubits(unsigned u) {
  union { unsigned u; float f; } v; v.u = u; return v.f;
}
static __device__ __forceinline__ float b2f(unsigned short s) {
  return ubits((unsigned)s << 16);
}

// ---------------- fold BN into second linear, write transposed bf16 ----------------
__global__ __launch_bounds__(128) void fold_kernel(
    const float* __restrict__ mw2, const float* __restrict__ mb2,
    const float* __restrict__ mg, const float* __restrict__ mb,
    const float* __restrict__ mm, const float* __restrict__ mv,
    const float* __restrict__ uw2, const float* __restrict__ ub2,
    const float* __restrict__ ug, const float* __restrict__ ub,
    const float* __restrict__ um, const float* __restrict__ uv,
    unsigned short* __restrict__ mW2fT, float* __restrict__ mB2f,
    unsigned short* __restrict__ uW2fT, float* __restrict__ uB2f) {
  int l = blockIdx.x & 3;
  bool isu = blockIdx.x >= 4;
  const float* W2 = (isu ? uw2 : mw2) + (size_t)l * 128 * 128;
  const float* b2 = (isu ? ub2 : mb2) + l * 128;
  const float* gg = (isu ? ug : mg) + l * 128;
  const float* bb = (isu ? ub : mb) + l * 128;
  const float* mn = (isu ? um : mm) + l * 128;
  const float* vr = (isu ? uv : mv) + l * 128;
  unsigned short* WfT = (isu ? uW2fT : mW2fT) + (size_t)l * 128 * 128;
  float* Bf = (isu ? uB2f : mB2f) + l * 128;
  __shared__ float a[128], c[128];
  int d = threadIdx.x;
  float ad = gg[d] * rsqrtf(vr[d] + EPSBN);
  a[d] = ad;
  c[d] = bb[d] - mn[d] * ad;
  __syncthreads();
  float acc = b2[d];
  for (int k = 0; k < 128; ++k) {
    float w = W2[k * 128 + d];
    WfT[(size_t)d * 128 + k] = f2b(a[k] * w);  // [n][k] bf16
    acc = fmaf(c[k], w, acc);
  }
  Bf[d] = acc;
}

// ---------------- transpose W1ab / U1 to [n][k] bf16 ----------------
__global__ __launch_bounds__(256) void transp_kernel(
    const float* __restrict__ mw1, const float* __restrict__ uw1,
    unsigned short* __restrict__ W1abT, unsigned short* __restrict__ U1T) {
  int l = blockIdx.x & 3;
  bool isu = blockIdx.x >= 4;
  int tid = threadIdx.x;
  if (!isu) {
    const float* W = mw1 + (size_t)l * 260 * 128;
    unsigned short* T = W1abT + (size_t)l * 256 * 128;
    for (int i = tid; i < 256 * 128; i += 256) {
      int n = i >> 7, k = i & 127;
      float v = (n < 128) ? W[(size_t)k * 128 + n] : W[(size_t)(128 + k) * 128 + (n - 128)];
      T[i] = f2b(v);
    }
  } else {
    const float* W = uw1 + (size_t)l * 256 * 128;
    unsigned short* T = U1T + (size_t)l * 128 * 256;
    for (int i = tid; i < 128 * 256; i += 256) {
      int n = i >> 8, k = i & 255;
      T[i] = f2b(W[(size_t)k * 128 + n]);
    }
  }
}

// ---------------- input projection ----------------
__global__ __launch_bounds__(256) void lin_in_kernel(
    const float* __restrict__ x, const float* __restrict__ pos,
    const float* __restrict__ W, const float* __restrict__ b,
    float* __restrict__ h, int Nn) {
  int gi = blockIdx.x * 256 + threadIdx.x;
  if (gi >= Nn * 128) return;
  int n = gi >> 7, d = gi & 127;
  float acc = b[d];
#pragma unroll
  for (int j = 0; j < 11; ++j) acc = fmaf(x[(size_t)n * 11 + j], W[j * 128 + d], acc);
#pragma unroll
  for (int j = 0; j < 3; ++j) acc = fmaf(pos[(size_t)n * 3 + j], W[(11 + j) * 128 + d], acc);
  h[gi] = acc;
}

// ---------------- counting sort of edges by dst ----------------
__global__ __launch_bounds__(256) void hist_kernel(const int* __restrict__ dst, int* __restrict__ count, int Ee) {
  int i = blockIdx.x * 256 + threadIdx.x;
  if (i < Ee) atomicAdd(&count[dst[i]], 1);
}

// 3-kernel parallel exclusive scan over count[n] -> cursor[n]
__global__ __launch_bounds__(1024) void scan1_kernel(
    const int* __restrict__ count, int* __restrict__ cursor, int* __restrict__ bsum, int n) {
  __shared__ int buf[1024];
  int i = blockIdx.x * 1024 + threadIdx.x;
  int v = (i < n) ? count[i] : 0;
  buf[threadIdx.x] = v;
  __syncthreads();
  for (int off = 1; off < 1024; off <<= 1) {
    int t = (threadIdx.x >= off) ? buf[threadIdx.x - off] : 0;
    __syncthreads();
    buf[threadIdx.x] += t;
    __syncthreads();
  }
  if (i < n) cursor[i] = buf[threadIdx.x] - v;  // exclusive within block
  if (threadIdx.x == 1023) bsum[blockIdx.x] = buf[1023];
}
__global__ __launch_bounds__(1024) void scan2_kernel(int* __restrict__ bsum, int nb) {
  __shared__ int buf[1024];
  int v = (threadIdx.x < nb) ? bsum[threadIdx.x] : 0;
  buf[threadIdx.x] = v;
  __syncthreads();
  for (int off = 1; off < 1024; off <<= 1) {
    int t = (threadIdx.x >= off) ? buf[threadIdx.x - off] : 0;
    __syncthreads();
    buf[threadIdx.x] += t;
    __syncthreads();
  }
  if (threadIdx.x < nb) bsum[threadIdx.x] = buf[threadIdx.x] - v;  // exclusive
}
__global__ __launch_bounds__(1024) void scan3_kernel(
    int* __restrict__ cursor, const int* __restrict__ bsum, int n) {
  int i = blockIdx.x * 1024 + threadIdx.x;
  if (i < n) cursor[i] += bsum[blockIdx.x];
}

__global__ __launch_bounds__(256) void scatter_kernel(
    const int* __restrict__ src, const int* __restrict__ dst, const float* __restrict__ ea,
    int* __restrict__ cursor, int* __restrict__ dst_s, int* __restrict__ src_s,
    float* __restrict__ ea_s, int Ee) {
  int e = blockIdx.x * 256 + threadIdx.x;
  if (e >= Ee) return;
  int dn = dst[e];
  int pos = atomicAdd(&cursor[dn], 1);
  dst_s[pos] = dn;
  src_s[pos] = src[e];
  *(float4*)(ea_s + (size_t)pos * 4) = *(const float4*)(ea + (size_t)e * 4);
}

// ---------------- pq_kernel: P = h@W1a, Q = h@W1b (bf16 out, MFMA) ----------------
__global__ __launch_bounds__(256) void pq_kernel(
    const float* __restrict__ h, const unsigned short* __restrict__ W1abT,
    unsigned short* __restrict__ P, unsigned short* __restrict__ Q, int Nn) {
  __shared__ unsigned short hs[64 * TS];
  const int tid = threadIdx.x;
  const int row0 = blockIdx.x * 64;
  // stage h tile fp32 -> bf16 LDS
#pragma unroll
  for (int i = 0; i < 8; ++i) {
    int idx = tid + i * 256;
    int r = idx >> 5, c4 = (idx & 31) << 2;
    float4 v = make_float4(0.f, 0.f, 0.f, 0.f);
    if (row0 + r < Nn) v = *(const float4*)(h + (size_t)(row0 + r) * 128 + c4);
    *(uint2*)&hs[r * TS + c4] = make_uint2(pk2(v.x, v.y), pk2(v.z, v.w));
  }
  __syncthreads();
  const int lane = tid & 63, wv = tid >> 6;
  const int m16 = lane & 15, quad = lane >> 4;
  floatx4 acc[4][4];  // [mt][nt]
#pragma unroll
  for (int mt = 0; mt < 4; ++mt)
#pragma unroll
    for (int nt = 0; nt < 4; ++nt) acc[mt][nt] = (floatx4)(0.0f);
  const __bf16* WT = (const __bf16*)W1abT;
  const __bf16* TlB = (const __bf16*)hs;
#pragma unroll
  for (int kb = 0; kb < 4; ++kb) {
    bf16x8 a[4], w[4];
#pragma unroll
    for (int mt = 0; mt < 4; ++mt)
      a[mt] = *(const bf16x8*)(TlB + (16 * mt + m16) * TS + kb * 32 + quad * 8);
#pragma unroll
    for (int nt = 0; nt < 4; ++nt)
      w[nt] = *(const bf16x8*)(WT + (size_t)(64 * wv + 16 * nt + m16) * 128 + kb * 32 + quad * 8);
#pragma unroll
    for (int mt = 0; mt < 4; ++mt)
#pragma unroll
      for (int nt = 0; nt < 4; ++nt)
        acc[mt][nt] = __builtin_amdgcn_mfma_f32_16x16x32_bf16(w[nt], a[mt], acc[mt][nt], 0, 0, 0);
  }
  // epilogue: lane holds row = row0+16mt+m16, cols n0..n0+3
#pragma unroll
  for (int mt = 0; mt < 4; ++mt) {
    int row = row0 + 16 * mt + m16;
    if (row >= Nn) continue;
#pragma unroll
    for (int nt = 0; nt < 4; ++nt) {
      int n0 = 64 * wv + 16 * nt + 4 * quad;
      floatx4 A = acc[mt][nt];
      uint2 o = make_uint2(pk2(A[0], A[1]), pk2(A[2], A[3]));
      if (n0 < 128) *(uint2*)(P + (size_t)row * 128 + n0) = o;
      else *(uint2*)(Q + (size_t)row * 128 + (n0 - 128)) = o;
    }
  }
}

// ---------------- edge message kernel (MFMA bf16, single shared tile) ----------------
__global__ __launch_bounds__(256) void edge_kernel(
    const unsigned short* __restrict__ P, const unsigned short* __restrict__ Q,
    const float* __restrict__ ea_s, const int* __restrict__ dst_s, const int* __restrict__ src_s,
    const float* __restrict__ W1c, const float* __restrict__ b1,
    const unsigned short* __restrict__ W2fT, const float* __restrict__ B2f,
    float* __restrict__ aggr, int Ee) {
  __shared__ unsigned short Tl[64 * TS];   // t tile, then reused for m tile
  __shared__ float sea[64 * 4];
  __shared__ int sdst[64], ssrc[64];
  const int tid = threadIdx.x;
  const int e0 = blockIdx.x * 64;
  if (tid < 64) {
    int e = e0 + tid;
    bool ok = e < Ee;
    sdst[tid] = ok ? dst_s[e] : -1;
    ssrc[tid] = ok ? src_s[e] : 0;
    float4 ev = ok ? *(const float4*)(ea_s + (size_t)e * 4) : make_float4(0.f, 0.f, 0.f, 0.f);
    *(float4*)&sea[tid * 4] = ev;
  }
  // per-thread W1c slice: cols c0..c0+7 (vector loads)
  const int rw = tid >> 4, c0 = (tid & 15) << 3;
  float wc[4][8], b1r[8];
#pragma unroll
  for (int r = 0; r < 4; ++r) {
    *(float4*)&wc[r][0] = *(const float4*)(W1c + r * 128 + c0);
    *(float4*)&wc[r][4] = *(const float4*)(W1c + r * 128 + c0 + 4);
  }
  *(float4*)&b1r[0] = *(const float4*)(b1 + c0);
  *(float4*)&b1r[4] = *(const float4*)(b1 + c0 + 4);
  __syncthreads();

  // ---- Phase A: t = relu(P[dst]+Q[src]+ea@W1c+b1) -> bf16 Tl ----
#pragma unroll
  for (int p = 0; p < 4; ++p) {
    int row = 16 * p + rw;
    int dn = sdst[row];
    uint4 out = make_uint4(0u, 0u, 0u, 0u);
    if (dn >= 0) {
      int sn = ssrc[row];
      uint4 pv = *(const uint4*)(P + (size_t)dn * 128 + c0);
      uint4 qv = *(const uint4*)(Q + (size_t)sn * 128 + c0);
      float e0f = sea[row * 4 + 0], e1f = sea[row * 4 + 1];
      float e2f = sea[row * 4 + 2], e3f = sea[row * 4 + 3];
      unsigned pu[4] = {pv.x, pv.y, pv.z, pv.w};
      unsigned qu[4] = {qv.x, qv.y, qv.z, qv.w};
      unsigned ou[4];
#pragma unroll
      for (int g = 0; g < 4; ++g) {
        float plo = ubits(pu[g] << 16), phi = ubits(pu[g] & 0xffff0000u);
        float qlo = ubits(qu[g] << 16), qhi = ubits(qu[g] & 0xffff0000u);
        int j0 = 2 * g, j1 = 2 * g + 1;
        float t0 = plo + qlo + b1r[j0];
        float t1 = phi + qhi + b1r[j1];
        t0 = fmaf(e0f, wc[0][j0], fmaf(e1f, wc[1][j0], fmaf(e2f, wc[2][j0], fmaf(e3f, wc[3][j0], t0))));
        t1 = fmaf(e0f, wc[0][j1], fmaf(e1f, wc[1][j1], fmaf(e2f, wc[2][j1], fmaf(e3f, wc[3][j1], t1))));
        ou[g] = pk2(fmaxf(t0, 0.f), fmaxf(t1, 0.f));
      }
      out = make_uint4(ou[0], ou[1], ou[2], ou[3]);
    }
    *(uint4*)&Tl[row * TS + c0] = out;
  }
  __syncthreads();

  // ---- Phase B: m = T @ W2f (operand-swapped MFMA) ----
  const int lane = tid & 63, wv = tid >> 6;
  const int m16 = lane & 15, quad = lane >> 4;
  floatx4 acc[4][2];
#pragma unroll
  for (int mt = 0; mt < 4; ++mt) { acc[mt][0] = (floatx4)(0.0f); acc[mt][1] = (floatx4)(0.0f); }
  const __bf16* WT = (const __bf16*)W2fT;
  const __bf16* TlB = (const __bf16*)Tl;
#pragma unroll
  for (int kb = 0; kb < 4; ++kb) {
    bf16x8 w0 = *(const bf16x8*)(WT + (size_t)(32 * wv + m16) * 128 + kb * 32 + quad * 8);
    bf16x8 w1 = *(const bf16x8*)(WT + (size_t)(32 * wv + 16 + m16) * 128 + kb * 32 + quad * 8);
    bf16x8 a[4];
#pragma unroll
    for (int mt = 0; mt < 4; ++mt)
      a[mt] = *(const bf16x8*)(TlB + (16 * mt + m16) * TS + kb * 32 + quad * 8);
#pragma unroll
    for (int mt = 0; mt < 4; ++mt) {
      acc[mt][0] = __builtin_amdgcn_mfma_f32_16x16x32_bf16(w0, a[mt], acc[mt][0], 0, 0, 0);
      acc[mt][1] = __builtin_amdgcn_mfma_f32_16x16x32_bf16(w1, a[mt], acc[mt][1], 0, 0, 0);
    }
  }
  __syncthreads();  // all MFMA A-reads of Tl complete -> safe to overwrite with m
  // epilogue: relu(acc + b2f) -> bf16 back into Tl
  {
    int n0 = 32 * wv + 4 * quad;
    float4 bv0 = *(const float4*)(B2f + n0);
    float4 bv1 = *(const float4*)(B2f + n0 + 16);
#pragma unroll
    for (int mt = 0; mt < 4; ++mt) {
      int row = 16 * mt + m16;
      floatx4 A0 = acc[mt][0], A1 = acc[mt][1];
      *(uint2*)&Tl[row * TS + n0] =
          make_uint2(pk2(fmaxf(A0[0] + bv0.x, 0.f), fmaxf(A0[1] + bv0.y, 0.f)),
                     pk2(fmaxf(A0[2] + bv0.z, 0.f), fmaxf(A0[3] + bv0.w, 0.f)));
      *(uint2*)&Tl[row * TS + n0 + 16] =
          make_uint2(pk2(fmaxf(A1[0] + bv1.x, 0.f), fmaxf(A1[1] + bv1.y, 0.f)),
                     pk2(fmaxf(A1[2] + bv1.z, 0.f), fmaxf(A1[3] + bv1.w, 0.f)));
    }
  }
  __syncthreads();

  // ---- Phase C: segmented reduce over equal-dst runs ----
  const int d = tid & 127, half = tid >> 7;
  const int dfirst = sdst[0], dlast = sdst[63];
  for (int s = half; s < 64; s += 2) {
    int dn = sdst[s];
    if (dn < 0) continue;
    if (s > 0 && sdst[s - 1] == dn) continue;  // not a segment start
    float sum = 0.f;
    int e = s;
    do { sum += b2f(Tl[e * TS + d]); ++e; } while (e < 64 && sdst[e] == dn);
    float* ap = aggr + (size_t)dn * 128 + d;
    if (dn == dfirst || dn == dlast) atomicAdd(ap, sum);
    else *ap = sum;  // all edges of dn are inside this tile
  }
}

// ---------------- fused update MLP (MFMA, in-place h) ----------------
__global__ __launch_bounds__(256) void upd_kernel(
    float* __restrict__ h, const float* __restrict__ aggr,
    const unsigned short* __restrict__ U1T, const float* __restrict__ ub1,
    const unsigned short* __restrict__ uW2fT, const float* __restrict__ uB2f, int Nn) {
  __shared__ unsigned short as_[64 * AS];  // [h|aggr] staging; u1 overlaid after pass 1
  const int tid = threadIdx.x;
  const int row0 = blockIdx.x * 64;
  // stage [h | aggr] -> bf16 LDS (K=256)
#pragma unroll
  for (int i = 0; i < 8; ++i) {
    int idx = tid + i * 256;
    int r = idx >> 5, c4 = (idx & 31) << 2;
    float4 v = make_float4(0.f, 0.f, 0.f, 0.f);
    if (row0 + r < Nn) v = *(const float4*)(h + (size_t)(row0 + r) * 128 + c4);
    *(uint2*)&as_[r * AS + c4] = make_uint2(pk2(v.x, v.y), pk2(v.z, v.w));
  }
#pragma unroll
  for (int i = 0; i < 8; ++i) {
    int idx = tid + i * 256;
    int r = idx >> 5, c4 = (idx & 31) << 2;
    float4 v = make_float4(0.f, 0.f, 0.f, 0.f);
    if (row0 + r < Nn) v = *(const float4*)(aggr + (size_t)(row0 + r) * 128 + c4);
    *(uint2*)&as_[r * AS + 128 + c4] = make_uint2(pk2(v.x, v.y), pk2(v.z, v.w));
  }
  __syncthreads();
  const int lane = tid & 63, wv = tid >> 6;
  const int m16 = lane & 15, quad = lane >> 4;
  const __bf16* asB = (const __bf16*)as_;
  unsigned short* u1s = as_;  // overlay (safe: written only after pass-1 reads)
  // pass 1: u1 = relu([h|aggr]@U1 + ub1), K=256
  {
    floatx4 acc[4][2];
#pragma unroll
    for (int mt = 0; mt < 4; ++mt) { acc[mt][0] = (floatx4)(0.0f); acc[mt][1] = (floatx4)(0.0f); }
    const __bf16* WT = (const __bf16*)U1T;
#pragma unroll
    for (int kb = 0; kb < 8; ++kb) {
      bf16x8 w0 = *(const bf16x8*)(WT + (size_t)(32 * wv + m16) * 256 + kb * 32 + quad * 8);
      bf16x8 w1 = *(const bf16x8*)(WT + (size_t)(32 * wv + 16 + m16) * 256 + kb * 32 + quad * 8);
      bf16x8 a[4];
#pragma unroll
      for (int mt = 0; mt < 4; ++mt)
        a[mt] = *(const bf16x8*)(asB + (16 * mt + m16) * AS + kb * 32 + quad * 8);
#pragma unroll
      for (int mt = 0; mt < 4; ++mt) {
        acc[mt][0] = __builtin_amdgcn_mfma_f32_16x16x32_bf16(w0, a[mt], acc[mt][0], 0, 0, 0);
        acc[mt][1] = __builtin_amdgcn_mfma_f32_16x16x32_bf16(w1, a[mt], acc[mt][1], 0, 0, 0);
      }
    }
    __syncthreads();  // pass-1 reads of as_ complete -> safe to overlay u1
    int n0 = 32 * wv + 4 * quad;
    float4 bv0 = *(const float4*)(ub1 + n0);
    float4 bv1 = *(const float4*)(ub1 + n0 + 16);
#pragma unroll
    for (int mt = 0; mt < 4; ++mt) {
      int row = 16 * mt + m16;
      floatx4 A0 = acc[mt][0], A1 = acc[mt][1];
      *(uint2*)&u1s[row * TS + n0] =
          make_uint2(pk2(fmaxf(A0[0] + bv0.x, 0.f), fmaxf(A0[1] + bv0.y, 0.f)),
                     pk2(fmaxf(A0[2] + bv0.z, 0.f), fmaxf(A0[3] + bv0.w, 0.f)));
      *(uint2*)&u1s[row * TS + n0 + 16] =
          make_uint2(pk2(fmaxf(A1[0] + bv1.x, 0.f), fmaxf(A1[1] + bv1.y, 0.f)),
                     pk2(fmaxf(A1[2] + bv1.z, 0.f), fmaxf(A1[3] + bv1.w, 0.f)));
    }
  }
  __syncthreads();
  // pass 2: h += relu(u1@U2f + uB2f), K=128
  {
    floatx4 acc[4][2];
#pragma unroll
    for (int mt = 0; mt < 4; ++mt) { acc[mt][0] = (floatx4)(0.0f); acc[mt][1] = (floatx4)(0.0f); }
    const __bf16* WT = (const __bf16*)uW2fT;
    const __bf16* u1B = (const __bf16*)u1s;
#pragma unroll
    for (int kb = 0; kb < 4; ++kb) {
      bf16x8 w0 = *(const bf16x8*)(WT + (size_t)(32 * wv + m16) * 128 + kb * 32 + quad * 8);
      bf16x8 w1 = *(const bf16x8*)(WT + (size_t)(32 * wv + 16 + m16) * 128 + kb * 32 + quad * 8);
      bf16x8 a[4];
#pragma unroll
      for (int mt = 0; mt < 4; ++mt)
        a[mt] = *(const bf16x8*)(u1B + (16 * mt + m16) * TS + kb * 32 + quad * 8);
#pragma unroll
      for (int mt = 0; mt < 4; ++mt) {
        acc[mt][0] = __builtin_amdgcn_mfma_f32_16x16x32_bf16(w0, a[mt], acc[mt][0], 0, 0, 0);
        acc[mt][1] = __builtin_amdgcn_mfma_f32_16x16x32_bf16(w1, a[mt], acc[mt][1], 0, 0, 0);
      }
    }
    int n0 = 32 * wv + 4 * quad;
    float4 bv0 = *(const float4*)(uB2f + n0);
    float4 bv1 = *(const float4*)(uB2f + n0 + 16);
#pragma unroll
    for (int mt = 0; mt < 4; ++mt) {
      int row = row0 + 16 * mt + m16;
      if (row >= Nn) continue;
      floatx4 A0 = acc[mt][0], A1 = acc[mt][1];
      float* hp0 = h + (size_t)row * 128 + n0;
      float4 hv0 = *(float4*)hp0;
      *(float4*)hp0 = make_float4(hv0.x + fmaxf(A0[0] + bv0.x, 0.f), hv0.y + fmaxf(A0[1] + bv0.y, 0.f),
                                  hv0.z + fmaxf(A0[2] + bv0.z, 0.f), hv0.w + fmaxf(A0[3] + bv0.w, 0.f));
      float* hp1 = hp0 + 16;
      float4 hv1 = *(float4*)hp1;
      *(float4*)hp1 = make_float4(hv1.x + fmaxf(A1[0] + bv1.x, 0.f), hv1.y + fmaxf(A1[1] + bv1.y, 0.f),
                                  hv1.z + fmaxf(A1[2] + bv1.z, 0.f), hv1.w + fmaxf(A1[3] + bv1.w, 0.f));
    }
  }
}

// ---------------- pooling ----------------
__global__ __launch_bounds__(128) void pool_sum_kernel(
    const float* __restrict__ h, const int* __restrict__ batch,
    float* __restrict__ sums, int* __restrict__ gcnt, int Nn) {
  int n0 = blockIdx.x * 256;
  if (n0 >= Nn) return;
  int nend = min(n0 + 256, Nn);
  int d = threadIdx.x;
  int gcur = batch[n0];
  float run = 0.f;
  int cnt = 0;
  for (int n = n0; n < nend; ++n) {
    int g = batch[n];
    if (g != gcur) {
      atomicAdd(&sums[(size_t)gcur * 128 + d], run);
      if (d == 0) atomicAdd(&gcnt[gcur], cnt);
      run = 0.f; cnt = 0; gcur = g;
    }
    run += h[(size_t)n * 128 + d];
    cnt += 1;
  }
  atomicAdd(&sums[(size_t)gcur * 128 + d], run);
  if (d == 0) atomicAdd(&gcnt[gcur], cnt);
}

__global__ __launch_bounds__(128) void pred_kernel(
    const float* __restrict__ sums, const int* __restrict__ gcnt,
    const float* __restrict__ pw, const float* __restrict__ pb, float* __restrict__ out) {
  __shared__ float red[2];
  int g = blockIdx.x, d = threadIdx.x;
  float c = fmaxf((float)gcnt[g], 1.f);
  float v = (sums[(size_t)g * 128 + d] / c) * pw[d];
  for (int o = 32; o > 0; o >>= 1) v += __shfl_down(v, o, 64);
  if ((d & 63) == 0) red[d >> 6] = v;
  __syncthreads();
  if (d == 0) out[g] = red[0] + red[1] + pb[0];
}

// ---------------- launch ----------------
extern "C" void kernel_launch(void* const* d_in, const int* in_sizes, int n_in,
                              void* d_out, int out_size, void* d_ws, size_t ws_size,
                              hipStream_t stream) {
  const float* x = (const float*)d_in[0];
  const float* pos = (const float*)d_in[1];
  const int* ei = (const int*)d_in[2];
  const float* ea = (const float*)d_in[3];
  const int* batch = (const int*)d_in[4];
  const float* lin_w = (const float*)d_in[5];
  const float* lin_b = (const float*)d_in[6];
  const float* mw1 = (const float*)d_in[7];
  const float* mb1 = (const float*)d_in[8];
  const float* mg = (const float*)d_in[9];
  const float* mbb = (const float*)d_in[10];
  const float* mm = (const float*)d_in[11];
  const float* mv = (const float*)d_in[12];
  const float* mw2 = (const float*)d_in[13];
  const float* mb2 = (const float*)d_in[14];
  const float* uw1 = (const float*)d_in[15];
  const float* ub1 = (const float*)d_in[16];
  const float* ug = (const float*)d_in[17];
  const float* ubb = (const float*)d_in[18];
  const float* um = (const float*)d_in[19];
  const float* uv = (const float*)d_in[20];
  const float* uw2 = (const float*)d_in[21];
  const float* ub2 = (const float*)d_in[22];
  const float* pw = (const float*)d_in[23];
  const float* pb = (const float*)d_in[24];
  float* out = (float*)d_out;

  const int Nn = in_sizes[0] / 11;
  const int Ee = in_sizes[3] / 4;
  const int* srcp = ei;        // edge_index[0] = source j
  const int* dstp = ei + Ee;   // edge_index[1] = target i

  char* wsb = (char*)d_ws;
  size_t off = 0;
  auto alloc = [&](size_t bytes) -> void* {
    void* p = wsb + off;
    off = (off + bytes + 255) & ~(size_t)255;
    return p;
  };
  float* h = (float*)alloc((size_t)Nn * 128 * 4);
  unsigned short* Pb = (unsigned short*)alloc((size_t)Nn * 128 * 2);
  unsigned short* Qb = (unsigned short*)alloc((size_t)Nn * 128 * 2);
  float* aggr = (float*)alloc((size_t)Nn * 128 * 4);
  int* dst_s = (int*)alloc((size_t)Ee * 4);
  int* src_s = (int*)alloc((size_t)Ee * 4);
  float* ea_s = (float*)alloc((size_t)Ee * 16);
  int* count = (int*)alloc((size_t)Nn * 4);
  int* cursor = (int*)alloc((size_t)Nn * 4);
  int* bsum = (int*)alloc((size_t)1024 * 4);
  unsigned short* mW2fT = (unsigned short*)alloc((size_t)4 * 128 * 128 * 2);
  unsigned short* uW2fT = (unsigned short*)alloc((size_t)4 * 128 * 128 * 2);
  unsigned short* W1abT = (unsigned short*)alloc((size_t)4 * 256 * 128 * 2);
  unsigned short* U1T = (unsigned short*)alloc((size_t)4 * 128 * 256 * 2);
  float* mB2f = (float*)alloc((size_t)4 * 128 * 4);
  float* uB2f = (float*)alloc((size_t)4 * 128 * 4);
  float* sums = (float*)alloc((size_t)out_size * 128 * 4);
  int* gcnt = (int*)alloc((size_t)out_size * 4);
  (void)ws_size; (void)n_in;

  fold_kernel<<<8, 128, 0, stream>>>(mw2, mb2, mg, mbb, mm, mv,
                                     uw2, ub2, ug, ubb, um, uv,
                                     mW2fT, mB2f, uW2fT, uB2f);
  transp_kernel<<<8, 256, 0, stream>>>(mw1, uw1, W1abT, U1T);
  lin_in_kernel<<<(Nn * 128 + 255) / 256, 256, 0, stream>>>(x, pos, lin_w, lin_b, h, Nn);

  hipMemsetAsync(count, 0, (size_t)Nn * 4, stream);
  hist_kernel<<<(Ee + 255) / 256, 256, 0, stream>>>(dstp, count, Ee);
  const int NB = (Nn + 1023) / 1024;
  scan1_kernel<<<NB, 1024, 0, stream>>>(count, cursor, bsum, Nn);
  scan2_kernel<<<1, 1024, 0, stream>>>(bsum, NB);
  scan3_kernel<<<NB, 1024, 0, stream>>>(cursor, bsum, Nn);
  scatter_kernel<<<(Ee + 255) / 256, 256, 0, stream>>>(srcp, dstp, ea, cursor,
                                                       dst_s, src_s, ea_s, Ee);

  const int gN = (Nn + 63) / 64;
  for (int l = 0; l < 4; ++l) {
    pq_kernel<<<gN, 256, 0, stream>>>(h, W1abT + (size_t)l * 256 * 128, Pb, Qb, Nn);
    hipMemsetAsync(aggr, 0, (size_t)Nn * 128 * 4, stream);
    edge_kernel<<<(Ee + 63) / 64, 256, 0, stream>>>(
        Pb, Qb, ea_s, dst_s, src_s,
        mw1 + (size_t)l * 260 * 128 + 256 * 128, mb1 + l * 128,
        mW2fT + (size_t)l * 16384, mB2f + l * 128, aggr, Ee);
    upd_kernel<<<gN, 256, 0, stream>>>(h, aggr,
                                       U1T + (size_t)l * 128 * 256, ub1 + l * 128,
                                       uW2fT + (size_t)l * 16384, uB2f + l * 128, Nn);
  }

  hipMemsetAsync(sums, 0, (size_t)out_size * 128 * 4, stream);
  hipMemsetAsync(gcnt, 0, (size_t)out_size * 4, stream);
  pool_sum_kernel<<<(Nn + 255) / 256, 128, 0, stream>>>(h, batch, sums, gcnt, Nn);
  pred_kernel<<<out_size, 128, 0, stream>>>(sums, gcnt, pw, pb, out);
}

// Round 5
// 2179.930 us; speedup vs baseline: 3.0639x; 1.0632x over previous
//
#include <hip/hip_runtime.h>
#include <hip/hip_bf16.h>

// MPNN: N=100000 nodes, E=1600000 edges, D=128, L=4, G=64.
// All GEMM-shaped work on MFMA bf16 (fp32 accumulate), fp32 residual stream h.
//   prep: fold BN into W2 (both MLPs), transpose all B-matrices to [n][k] bf16,
//         counting-sort edges by dst, per-64-edge-tile segment-start bitmasks.
//   per layer:
//     edge_kernel: t = relu(P[dst]+Q[src]+ea@W1c+b1) -> bf16 LDS (Tl)
//                  m = relu(t@W2f+b2f)   (MFMA) -> written back into Tl
//                  mask-driven segmented reduce (b128, 8 cols/thread) -> aggr
//     upd_kernel:  u1 = relu([h|aggr]@U1+ub1) (MFMA K=256) -> bf16 LDS overlay
//                  h += relu(u1@U2f+uB2f)     (MFMA K=128), in-place
//                  + fused next-layer P/Q = h_new @ W1ab (via LDS h_new tile)
// MFMA operand swap: acc = mfma(Wfrag, actFrag, acc) gives D[n][m]: lane holds
// (edge-row = lane&15, 4 consecutive out-cols = quad*4+reg) -> row-major stores.

#define EPSBN 1e-5f
#define TS 136   // bf16 elems per LDS row for 128-wide tiles (272 B = 17*16 B)
#define AS 264   // bf16 elems per LDS row for 256-wide tiles (528 B = 33*16 B)

typedef __bf16 bf16x8 __attribute__((ext_vector_type(8)));
typedef float floatx4 __attribute__((ext_vector_type(4)));

static __device__ __forceinline__ unsigned short f2b(float f) {
  union { float f; unsigned u; } v; v.f = f;
  unsigned u = v.u;
  return (unsigned short)((u + 0x7fffu + ((u >> 16) & 1u)) >> 16);  // RNE
}
static __device__ __forceinline__ unsigned pk2(float lo, float hi) {
  union { __hip_bfloat162 h; unsigned u; } v;
  v.h = __float22bfloat162_rn(make_float2(lo, hi));  // v_cvt_pk_bf16_f32
  return v.u;
}
static __device__ __forceinline__ float ubits(unsigned u) {
  union { unsigned u; float f; } v; v.u = u; return v.f;
}

// ---------------- fold BN into second linear, write transposed bf16 ----------------
__global__ __launch_bounds__(128) void fold_kernel(
    const float* __restrict__ mw2, const float* __restrict__ mb2,
    const float* __restrict__ mg, const float* __restrict__ mb,
    const float* __restrict__ mm, const float* __restrict__ mv,
    const float* __restrict__ uw2, const float* __restrict__ ub2,
    const float* __restrict__ ug, const float* __restrict__ ub,
    const float* __restrict__ um, const float* __restrict__ uv,
    unsigned short* __restrict__ mW2fT, float* __restrict__ mB2f,
    unsigned short* __restrict__ uW2fT, float* __restrict__ uB2f) {
  int l = blockIdx.x & 3;
  bool isu = blockIdx.x >= 4;
  const float* W2 = (isu ? uw2 : mw2) + (size_t)l * 128 * 128;
  const float* b2 = (isu ? ub2 : mb2) + l * 128;
  const float* gg = (isu ? ug : mg) + l * 128;
  const float* bb = (isu ? ub : mb) + l * 128;
  const float* mn = (isu ? um : mm) + l * 128;
  const float* vr = (isu ? uv : mv) + l * 128;
  unsigned short* WfT = (isu ? uW2fT : mW2fT) + (size_t)l * 128 * 128;
  float* Bf = (isu ? uB2f : mB2f) + l * 128;
  __shared__ float a[128], c[128];
  int d = threadIdx.x;
  float ad = gg[d] * rsqrtf(vr[d] + EPSBN);
  a[d] = ad;
  c[d] = bb[d] - mn[d] * ad;
  __syncthreads();
  float acc = b2[d];
  for (int k = 0; k < 128; ++k) {
    float w = W2[k * 128 + d];
    WfT[(size_t)d * 128 + k] = f2b(a[k] * w);  // [n][k] bf16
    acc = fmaf(c[k], w, acc);
  }
  Bf[d] = acc;
}

// ---------------- transpose W1ab / U1 to [n][k] bf16 ----------------
__global__ __launch_bounds__(256) void transp_kernel(
    const float* __restrict__ mw1, const float* __restrict__ uw1,
    unsigned short* __restrict__ W1abT, unsigned short* __restrict__ U1T) {
  int l = blockIdx.x & 3;
  bool isu = blockIdx.x >= 4;
  int tid = threadIdx.x;
  if (!isu) {
    const float* W = mw1 + (size_t)l * 260 * 128;
    unsigned short* T = W1abT + (size_t)l * 256 * 128;
    for (int i = tid; i < 256 * 128; i += 256) {
      int n = i >> 7, k = i & 127;
      float v = (n < 128) ? W[(size_t)k * 128 + n] : W[(size_t)(128 + k) * 128 + (n - 128)];
      T[i] = f2b(v);
    }
  } else {
    const float* W = uw1 + (size_t)l * 256 * 128;
    unsigned short* T = U1T + (size_t)l * 128 * 256;
    for (int i = tid; i < 128 * 256; i += 256) {
      int n = i >> 8, k = i & 255;
      T[i] = f2b(W[(size_t)k * 128 + n]);
    }
  }
}

// ---------------- input projection ----------------
__global__ __launch_bounds__(256) void lin_in_kernel(
    const float* __restrict__ x, const float* __restrict__ pos,
    const float* __restrict__ W, const float* __restrict__ b,
    float* __restrict__ h, int Nn) {
  int gi = blockIdx.x * 256 + threadIdx.x;
  if (gi >= Nn * 128) return;
  int n = gi >> 7, d = gi & 127;
  float acc = b[d];
#pragma unroll
  for (int j = 0; j < 11; ++j) acc = fmaf(x[(size_t)n * 11 + j], W[j * 128 + d], acc);
#pragma unroll
  for (int j = 0; j < 3; ++j) acc = fmaf(pos[(size_t)n * 3 + j], W[(11 + j) * 128 + d], acc);
  h[gi] = acc;
}

// ---------------- counting sort of edges by dst ----------------
__global__ __launch_bounds__(256) void hist_kernel(const int* __restrict__ dst, int* __restrict__ count, int Ee) {
  int i = blockIdx.x * 256 + threadIdx.x;
  if (i < Ee) atomicAdd(&count[dst[i]], 1);
}

// 3-kernel parallel exclusive scan over count[n] -> cursor[n]
__global__ __launch_bounds__(1024) void scan1_kernel(
    const int* __restrict__ count, int* __restrict__ cursor, int* __restrict__ bsum, int n) {
  __shared__ int buf[1024];
  int i = blockIdx.x * 1024 + threadIdx.x;
  int v = (i < n) ? count[i] : 0;
  buf[threadIdx.x] = v;
  __syncthreads();
  for (int off = 1; off < 1024; off <<= 1) {
    int t = (threadIdx.x >= off) ? buf[threadIdx.x - off] : 0;
    __syncthreads();
    buf[threadIdx.x] += t;
    __syncthreads();
  }
  if (i < n) cursor[i] = buf[threadIdx.x] - v;  // exclusive within block
  if (threadIdx.x == 1023) bsum[blockIdx.x] = buf[1023];
}
__global__ __launch_bounds__(1024) void scan2_kernel(int* __restrict__ bsum, int nb) {
  __shared__ int buf[1024];
  int v = (threadIdx.x < nb) ? bsum[threadIdx.x] : 0;
  buf[threadIdx.x] = v;
  __syncthreads();
  for (int off = 1; off < 1024; off <<= 1) {
    int t = (threadIdx.x >= off) ? buf[threadIdx.x - off] : 0;
    __syncthreads();
    buf[threadIdx.x] += t;
    __syncthreads();
  }
  if (threadIdx.x < nb) bsum[threadIdx.x] = buf[threadIdx.x] - v;  // exclusive
}
__global__ __launch_bounds__(1024) void scan3_kernel(
    int* __restrict__ cursor, const int* __restrict__ bsum, int n) {
  int i = blockIdx.x * 1024 + threadIdx.x;
  if (i < n) cursor[i] += bsum[blockIdx.x];
}

__global__ __launch_bounds__(256) void scatter_kernel(
    const int* __restrict__ src, const int* __restrict__ dst, const float* __restrict__ ea,
    int* __restrict__ cursor, int* __restrict__ dst_s, int* __restrict__ src_s,
    float* __restrict__ ea_s, int Ee) {
  int e = blockIdx.x * 256 + threadIdx.x;
  if (e >= Ee) return;
  int dn = dst[e];
  int pos = atomicAdd(&cursor[dn], 1);
  dst_s[pos] = dn;
  src_s[pos] = src[e];
  *(float4*)(ea_s + (size_t)pos * 4) = *(const float4*)(ea + (size_t)e * 4);
}

// per-64-edge-tile segment-start bitmask (bit i = edge 64T+i starts a run)
__global__ __launch_bounds__(256) void mask_kernel(
    const int* __restrict__ dst_s, unsigned long long* __restrict__ masks, int Ee, int nt) {
  int tile = blockIdx.x * 4 + (threadIdx.x >> 6);
  int lane = threadIdx.x & 63;
  if (tile >= nt) return;
  int e = tile * 64 + lane;
  bool start;
  if (e >= Ee || lane == 0) start = true;
  else start = (dst_s[e] != dst_s[e - 1]);
  unsigned long long m = __ballot(start);
  if (lane == 0) masks[tile] = m;
}

// ---------------- pq_kernel: P = h@W1a, Q = h@W1b (bf16 out, MFMA) ----------------
// (standalone for layer 0; later layers fused into upd_kernel)
__global__ __launch_bounds__(256) void pq_kernel(
    const float* __restrict__ h, const unsigned short* __restrict__ W1abT,
    unsigned short* __restrict__ P, unsigned short* __restrict__ Q, int Nn) {
  __shared__ unsigned short hs[64 * TS];
  const int tid = threadIdx.x;
  const int row0 = blockIdx.x * 64;
#pragma unroll
  for (int i = 0; i < 8; ++i) {
    int idx = tid + i * 256;
    int r = idx >> 5, c4 = (idx & 31) << 2;
    float4 v = make_float4(0.f, 0.f, 0.f, 0.f);
    if (row0 + r < Nn) v = *(const float4*)(h + (size_t)(row0 + r) * 128 + c4);
    *(uint2*)&hs[r * TS + c4] = make_uint2(pk2(v.x, v.y), pk2(v.z, v.w));
  }
  __syncthreads();
  const int lane = tid & 63, wv = tid >> 6;
  const int m16 = lane & 15, quad = lane >> 4;
  floatx4 acc[4][4];
#pragma unroll
  for (int mt = 0; mt < 4; ++mt)
#pragma unroll
    for (int nt = 0; nt < 4; ++nt) acc[mt][nt] = (floatx4)(0.0f);
  const __bf16* WT = (const __bf16*)W1abT;
  const __bf16* TlB = (const __bf16*)hs;
#pragma unroll
  for (int kb = 0; kb < 4; ++kb) {
    bf16x8 a[4], w[4];
#pragma unroll
    for (int mt = 0; mt < 4; ++mt)
      a[mt] = *(const bf16x8*)(TlB + (16 * mt + m16) * TS + kb * 32 + quad * 8);
#pragma unroll
    for (int nt = 0; nt < 4; ++nt)
      w[nt] = *(const bf16x8*)(WT + (size_t)(64 * wv + 16 * nt + m16) * 128 + kb * 32 + quad * 8);
#pragma unroll
    for (int mt = 0; mt < 4; ++mt)
#pragma unroll
      for (int nt = 0; nt < 4; ++nt)
        acc[mt][nt] = __builtin_amdgcn_mfma_f32_16x16x32_bf16(w[nt], a[mt], acc[mt][nt], 0, 0, 0);
  }
#pragma unroll
  for (int mt = 0; mt < 4; ++mt) {
    int row = row0 + 16 * mt + m16;
    if (row >= Nn) continue;
#pragma unroll
    for (int nt = 0; nt < 4; ++nt) {
      int n0 = 64 * wv + 16 * nt + 4 * quad;
      floatx4 A = acc[mt][nt];
      uint2 o = make_uint2(pk2(A[0], A[1]), pk2(A[2], A[3]));
      if (n0 < 128) *(uint2*)(P + (size_t)row * 128 + n0) = o;
      else *(uint2*)(Q + (size_t)row * 128 + (n0 - 128)) = o;
    }
  }
}

// ---------------- edge message kernel (MFMA bf16, mask-driven reduce) ----------------
__global__ __launch_bounds__(256) void edge_kernel(
    const unsigned short* __restrict__ P, const unsigned short* __restrict__ Q,
    const float* __restrict__ ea_s, const int* __restrict__ dst_s, const int* __restrict__ src_s,
    const unsigned long long* __restrict__ masks,
    const float* __restrict__ W1c, const float* __restrict__ b1,
    const unsigned short* __restrict__ W2fT, const float* __restrict__ B2f,
    float* __restrict__ aggr, int Ee) {
  __shared__ unsigned short Tl[64 * TS];   // t tile, then reused for m tile
  __shared__ float sea[64 * 4];
  __shared__ int sdst[64], ssrc[64];
  const int tid = threadIdx.x;
  const int e0 = blockIdx.x * 64;
  const unsigned long long mask = masks[blockIdx.x];
  if (tid < 64) {
    int e = e0 + tid;
    bool ok = e < Ee;
    sdst[tid] = ok ? dst_s[e] : -1;
    ssrc[tid] = ok ? src_s[e] : 0;
    float4 ev = ok ? *(const float4*)(ea_s + (size_t)e * 4) : make_float4(0.f, 0.f, 0.f, 0.f);
    *(float4*)&sea[tid * 4] = ev;
  }
  // per-thread W1c slice: cols c0..c0+7 (vector loads)
  const int rw = tid >> 4, c0 = (tid & 15) << 3;
  float wc[4][8], b1r[8];
#pragma unroll
  for (int r = 0; r < 4; ++r) {
    *(float4*)&wc[r][0] = *(const float4*)(W1c + r * 128 + c0);
    *(float4*)&wc[r][4] = *(const float4*)(W1c + r * 128 + c0 + 4);
  }
  *(float4*)&b1r[0] = *(const float4*)(b1 + c0);
  *(float4*)&b1r[4] = *(const float4*)(b1 + c0 + 4);
  __syncthreads();

  // ---- Phase A: t = relu(P[dst]+Q[src]+ea@W1c+b1) -> bf16 Tl ----
#pragma unroll
  for (int p = 0; p < 4; ++p) {
    int row = 16 * p + rw;
    int dn = sdst[row];
    uint4 out = make_uint4(0u, 0u, 0u, 0u);
    if (dn >= 0) {
      int sn = ssrc[row];
      uint4 pv = *(const uint4*)(P + (size_t)dn * 128 + c0);
      uint4 qv = *(const uint4*)(Q + (size_t)sn * 128 + c0);
      float e0f = sea[row * 4 + 0], e1f = sea[row * 4 + 1];
      float e2f = sea[row * 4 + 2], e3f = sea[row * 4 + 3];
      unsigned pu[4] = {pv.x, pv.y, pv.z, pv.w};
      unsigned qu[4] = {qv.x, qv.y, qv.z, qv.w};
      unsigned ou[4];
#pragma unroll
      for (int g = 0; g < 4; ++g) {
        float plo = ubits(pu[g] << 16), phi = ubits(pu[g] & 0xffff0000u);
        float qlo = ubits(qu[g] << 16), qhi = ubits(qu[g] & 0xffff0000u);
        int j0 = 2 * g, j1 = 2 * g + 1;
        float t0 = plo + qlo + b1r[j0];
        float t1 = phi + qhi + b1r[j1];
        t0 = fmaf(e0f, wc[0][j0], fmaf(e1f, wc[1][j0], fmaf(e2f, wc[2][j0], fmaf(e3f, wc[3][j0], t0))));
        t1 = fmaf(e0f, wc[0][j1], fmaf(e1f, wc[1][j1], fmaf(e2f, wc[2][j1], fmaf(e3f, wc[3][j1], t1))));
        ou[g] = pk2(fmaxf(t0, 0.f), fmaxf(t1, 0.f));
      }
      out = make_uint4(ou[0], ou[1], ou[2], ou[3]);
    }
    *(uint4*)&Tl[row * TS + c0] = out;
  }
  __syncthreads();

  // ---- Phase B: m = T @ W2f (operand-swapped MFMA) ----
  const int lane = tid & 63, wv = tid >> 6;
  const int m16 = lane & 15, quad = lane >> 4;
  floatx4 acc[4][2];
#pragma unroll
  for (int mt = 0; mt < 4; ++mt) { acc[mt][0] = (floatx4)(0.0f); acc[mt][1] = (floatx4)(0.0f); }
  const __bf16* WT = (const __bf16*)W2fT;
  const __bf16* TlB = (const __bf16*)Tl;
#pragma unroll
  for (int kb = 0; kb < 4; ++kb) {
    bf16x8 w0 = *(const bf16x8*)(WT + (size_t)(32 * wv + m16) * 128 + kb * 32 + quad * 8);
    bf16x8 w1 = *(const bf16x8*)(WT + (size_t)(32 * wv + 16 + m16) * 128 + kb * 32 + quad * 8);
    bf16x8 a[4];
#pragma unroll
    for (int mt = 0; mt < 4; ++mt)
      a[mt] = *(const bf16x8*)(TlB + (16 * mt + m16) * TS + kb * 32 + quad * 8);
#pragma unroll
    for (int mt = 0; mt < 4; ++mt) {
      acc[mt][0] = __builtin_amdgcn_mfma_f32_16x16x32_bf16(w0, a[mt], acc[mt][0], 0, 0, 0);
      acc[mt][1] = __builtin_amdgcn_mfma_f32_16x16x32_bf16(w1, a[mt], acc[mt][1], 0, 0, 0);
    }
  }
  __syncthreads();  // all MFMA A-reads of Tl complete -> safe to overwrite with m
  // epilogue: relu(acc + b2f) -> bf16 back into Tl
  {
    int n0 = 32 * wv + 4 * quad;
    float4 bv0 = *(const float4*)(B2f + n0);
    float4 bv1 = *(const float4*)(B2f + n0 + 16);
#pragma unroll
    for (int mt = 0; mt < 4; ++mt) {
      int row = 16 * mt + m16;
      floatx4 A0 = acc[mt][0], A1 = acc[mt][1];
      *(uint2*)&Tl[row * TS + n0] =
          make_uint2(pk2(fmaxf(A0[0] + bv0.x, 0.f), fmaxf(A0[1] + bv0.y, 0.f)),
                     pk2(fmaxf(A0[2] + bv0.z, 0.f), fmaxf(A0[3] + bv0.w, 0.f)));
      *(uint2*)&Tl[row * TS + n0 + 16] =
          make_uint2(pk2(fmaxf(A1[0] + bv1.x, 0.f), fmaxf(A1[1] + bv1.y, 0.f)),
                     pk2(fmaxf(A1[2] + bv1.z, 0.f), fmaxf(A1[3] + bv1.w, 0.f)));
    }
  }
  __syncthreads();

  // ---- Phase C: mask-driven segmented reduce, 8 cols/thread, b128 reads ----
  const int cg8 = (tid & 15) << 3;  // 8-column group
  const int st = tid >> 4;          // starter slots st, st+16, st+32, st+48
  const int dfirst = sdst[0], dlast = sdst[63];
  for (int s = st; s < 64; s += 16) {
    if (!(mask & (1ull << s))) continue;  // not a segment start
    int dn = sdst[s];
    if (dn < 0) continue;
    int end;
    if (s >= 63) end = 64;
    else {
      unsigned long long m2 = mask >> (s + 1);
      end = m2 ? (s + 1 + (int)__builtin_ctzll(m2)) : 64;
    }
    float a0 = 0.f, a1 = 0.f, a2 = 0.f, a3 = 0.f, a4 = 0.f, a5 = 0.f, a6 = 0.f, a7 = 0.f;
    for (int e = s; e < end; ++e) {
      uint4 v = *(const uint4*)&Tl[e * TS + cg8];
      a0 += ubits(v.x << 16); a1 += ubits(v.x & 0xffff0000u);
      a2 += ubits(v.y << 16); a3 += ubits(v.y & 0xffff0000u);
      a4 += ubits(v.z << 16); a5 += ubits(v.z & 0xffff0000u);
      a6 += ubits(v.w << 16); a7 += ubits(v.w & 0xffff0000u);
    }
    float* ap = aggr + (size_t)dn * 128 + cg8;
    if (dn == dfirst || dn == dlast) {
      atomicAdd(ap + 0, a0); atomicAdd(ap + 1, a1);
      atomicAdd(ap + 2, a2); atomicAdd(ap + 3, a3);
      atomicAdd(ap + 4, a4); atomicAdd(ap + 5, a5);
      atomicAdd(ap + 6, a6); atomicAdd(ap + 7, a7);
    } else {
      *(float4*)ap = make_float4(a0, a1, a2, a3);
      *(float4*)(ap + 4) = make_float4(a4, a5, a6, a7);
    }
  }
}

// ---------------- fused update MLP (+ next-layer P/Q), MFMA, in-place h ----------------
__global__ __launch_bounds__(256) void upd_kernel(
    float* __restrict__ h, const float* __restrict__ aggr,
    const unsigned short* __restrict__ U1T, const float* __restrict__ ub1,
    const unsigned short* __restrict__ uW2fT, const float* __restrict__ uB2f, int Nn,
    const unsigned short* __restrict__ W1abT_next,
    unsigned short* __restrict__ P, unsigned short* __restrict__ Q) {
  __shared__ unsigned short as_[64 * AS];  // [h|aggr]; u1 overlay; then h_new overlay
  const int tid = threadIdx.x;
  const int row0 = blockIdx.x * 64;
#pragma unroll
  for (int i = 0; i < 8; ++i) {
    int idx = tid + i * 256;
    int r = idx >> 5, c4 = (idx & 31) << 2;
    float4 v = make_float4(0.f, 0.f, 0.f, 0.f);
    if (row0 + r < Nn) v = *(const float4*)(h + (size_t)(row0 + r) * 128 + c4);
    *(uint2*)&as_[r * AS + c4] = make_uint2(pk2(v.x, v.y), pk2(v.z, v.w));
  }
#pragma unroll
  for (int i = 0; i < 8; ++i) {
    int idx = tid + i * 256;
    int r = idx >> 5, c4 = (idx & 31) << 2;
    float4 v = make_float4(0.f, 0.f, 0.f, 0.f);
    if (row0 + r < Nn) v = *(const float4*)(aggr + (size_t)(row0 + r) * 128 + c4);
    *(uint2*)&as_[r * AS + 128 + c4] = make_uint2(pk2(v.x, v.y), pk2(v.z, v.w));
  }
  __syncthreads();
  const int lane = tid & 63, wv = tid >> 6;
  const int m16 = lane & 15, quad = lane >> 4;
  const __bf16* asB = (const __bf16*)as_;
  unsigned short* u1s = as_;  // overlay (TS stride)
  // pass 1: u1 = relu([h|aggr]@U1 + ub1), K=256
  {
    floatx4 acc[4][2];
#pragma unroll
    for (int mt = 0; mt < 4; ++mt) { acc[mt][0] = (floatx4)(0.0f); acc[mt][1] = (floatx4)(0.0f); }
    const __bf16* WT = (const __bf16*)U1T;
#pragma unroll
    for (int kb = 0; kb < 8; ++kb) {
      bf16x8 w0 = *(const bf16x8*)(WT + (size_t)(32 * wv + m16) * 256 + kb * 32 + quad * 8);
      bf16x8 w1 = *(const bf16x8*)(WT + (size_t)(32 * wv + 16 + m16) * 256 + kb * 32 + quad * 8);
      bf16x8 a[4];
#pragma unroll
      for (int mt = 0; mt < 4; ++mt)
        a[mt] = *(const bf16x8*)(asB + (16 * mt + m16) * AS + kb * 32 + quad * 8);
#pragma unroll
      for (int mt = 0; mt < 4; ++mt) {
        acc[mt][0] = __builtin_amdgcn_mfma_f32_16x16x32_bf16(w0, a[mt], acc[mt][0], 0, 0, 0);
        acc[mt][1] = __builtin_amdgcn_mfma_f32_16x16x32_bf16(w1, a[mt], acc[mt][1], 0, 0, 0);
      }
    }
    __syncthreads();  // pass-1 reads of as_ complete -> safe to overlay u1
    int n0 = 32 * wv + 4 * quad;
    float4 bv0 = *(const float4*)(ub1 + n0);
    float4 bv1 = *(const float4*)(ub1 + n0 + 16);
#pragma unroll
    for (int mt = 0; mt < 4; ++mt) {
      int row = 16 * mt + m16;
      floatx4 A0 = acc[mt][0], A1 = acc[mt][1];
      *(uint2*)&u1s[row * TS + n0] =
          make_uint2(pk2(fmaxf(A0[0] + bv0.x, 0.f), fmaxf(A0[1] + bv0.y, 0.f)),
                     pk2(fmaxf(A0[2] + bv0.z, 0.f), fmaxf(A0[3] + bv0.w, 0.f)));
      *(uint2*)&u1s[row * TS + n0 + 16] =
          make_uint2(pk2(fmaxf(A1[0] + bv1.x, 0.f), fmaxf(A1[1] + bv1.y, 0.f)),
                     pk2(fmaxf(A1[2] + bv1.z, 0.f), fmaxf(A1[3] + bv1.w, 0.f)));
    }
  }
  __syncthreads();
  // pass 2: h_new = h + relu(u1@U2f + uB2f), K=128; write global + LDS bf16
  {
    floatx4 acc[4][2];
#pragma unroll
    for (int mt = 0; mt < 4; ++mt) { acc[mt][0] = (floatx4)(0.0f); acc[mt][1] = (floatx4)(0.0f); }
    const __bf16* WT = (const __bf16*)uW2fT;
    const __bf16* u1B = (const __bf16*)u1s;
#pragma unroll
    for (int kb = 0; kb < 4; ++kb) {
      bf16x8 w0 = *(const bf16x8*)(WT + (size_t)(32 * wv + m16) * 128 + kb * 32 + quad * 8);
      bf16x8 w1 = *(const bf16x8*)(WT + (size_t)(32 * wv + 16 + m16) * 128 + kb * 32 + quad * 8);
      bf16x8 a[4];
#pragma unroll
      for (int mt = 0; mt < 4; ++mt)
        a[mt] = *(const bf16x8*)(u1B + (16 * mt + m16) * TS + kb * 32 + quad * 8);
#pragma unroll
      for (int mt = 0; mt < 4; ++mt) {
        acc[mt][0] = __builtin_amdgcn_mfma_f32_16x16x32_bf16(w0, a[mt], acc[mt][0], 0, 0, 0);
        acc[mt][1] = __builtin_amdgcn_mfma_f32_16x16x32_bf16(w1, a[mt], acc[mt][1], 0, 0, 0);
      }
    }
    __syncthreads();  // pass-2 reads of u1s complete -> safe to overlay h_new
    int n0 = 32 * wv + 4 * quad;
    float4 bv0 = *(const float4*)(uB2f + n0);
    float4 bv1 = *(const float4*)(uB2f + n0 + 16);
#pragma unroll
    for (int mt = 0; mt < 4; ++mt) {
      int rloc = 16 * mt + m16;
      int row = row0 + rloc;
      floatx4 A0 = acc[mt][0], A1 = acc[mt][1];
      if (row < Nn) {
        float* hp0 = h + (size_t)row * 128 + n0;
        float4 hv0 = *(float4*)hp0;
        float4 o0 = make_float4(hv0.x + fmaxf(A0[0] + bv0.x, 0.f), hv0.y + fmaxf(A0[1] + bv0.y, 0.f),
                                hv0.z + fmaxf(A0[2] + bv0.z, 0.f), hv0.w + fmaxf(A0[3] + bv0.w, 0.f));
        *(float4*)hp0 = o0;
        float* hp1 = hp0 + 16;
        float4 hv1 = *(float4*)hp1;
        float4 o1 = make_float4(hv1.x + fmaxf(A1[0] + bv1.x, 0.f), hv1.y + fmaxf(A1[1] + bv1.y, 0.f),
                                hv1.z + fmaxf(A1[2] + bv1.z, 0.f), hv1.w + fmaxf(A1[3] + bv1.w, 0.f));
        *(float4*)hp1 = o1;
        if (W1abT_next) {
          *(uint2*)&u1s[rloc * TS + n0] = make_uint2(pk2(o0.x, o0.y), pk2(o0.z, o0.w));
          *(uint2*)&u1s[rloc * TS + n0 + 16] = make_uint2(pk2(o1.x, o1.y), pk2(o1.z, o1.w));
        }
      } else if (W1abT_next) {
        *(uint2*)&u1s[rloc * TS + n0] = make_uint2(0u, 0u);
        *(uint2*)&u1s[rloc * TS + n0 + 16] = make_uint2(0u, 0u);
      }
    }
  }
  // fused next-layer P/Q from h_new tile in LDS
  if (W1abT_next) {
    __syncthreads();
    floatx4 pacc[4][4];
#pragma unroll
    for (int mt = 0; mt < 4; ++mt)
#pragma unroll
      for (int nt = 0; nt < 4; ++nt) pacc[mt][nt] = (floatx4)(0.0f);
    const __bf16* WT = (const __bf16*)W1abT_next;
    const __bf16* hB = (const __bf16*)u1s;
#pragma unroll
    for (int kb = 0; kb < 4; ++kb) {
      bf16x8 a[4], w[4];
#pragma unroll
      for (int mt = 0; mt < 4; ++mt)
        a[mt] = *(const bf16x8*)(hB + (16 * mt + m16) * TS + kb * 32 + quad * 8);
#pragma unroll
      for (int nt = 0; nt < 4; ++nt)
        w[nt] = *(const bf16x8*)(WT + (size_t)(64 * wv + 16 * nt + m16) * 128 + kb * 32 + quad * 8);
#pragma unroll
      for (int mt = 0; mt < 4; ++mt)
#pragma unroll
        for (int nt = 0; nt < 4; ++nt)
          pacc[mt][nt] = __builtin_amdgcn_mfma_f32_16x16x32_bf16(w[nt], a[mt], pacc[mt][nt], 0, 0, 0);
    }
#pragma unroll
    for (int mt = 0; mt < 4; ++mt) {
      int row = row0 + 16 * mt + m16;
      if (row >= Nn) continue;
#pragma unroll
      for (int nt = 0; nt < 4; ++nt) {
        int n0 = 64 * wv + 16 * nt + 4 * quad;
        floatx4 A = pacc[mt][nt];
        uint2 o = make_uint2(pk2(A[0], A[1]), pk2(A[2], A[3]));
        if (n0 < 128) *(uint2*)(P + (size_t)row * 128 + n0) = o;
        else *(uint2*)(Q + (size_t)row * 128 + (n0 - 128)) = o;
      }
    }
  }
}

// ---------------- pooling ----------------
__global__ __launch_bounds__(128) void pool_sum_kernel(
    const float* __restrict__ h, const int* __restrict__ batch,
    float* __restrict__ sums, int* __restrict__ gcnt, int Nn) {
  int n0 = blockIdx.x * 256;
  if (n0 >= Nn) return;
  int nend = min(n0 + 256, Nn);
  int d = threadIdx.x;
  int gcur = batch[n0];
  float run = 0.f;
  int cnt = 0;
  for (int n = n0; n < nend; ++n) {
    int g = batch[n];
    if (g != gcur) {
      atomicAdd(&sums[(size_t)gcur * 128 + d], run);
      if (d == 0) atomicAdd(&gcnt[gcur], cnt);
      run = 0.f; cnt = 0; gcur = g;
    }
    run += h[(size_t)n * 128 + d];
    cnt += 1;
  }
  atomicAdd(&sums[(size_t)gcur * 128 + d], run);
  if (d == 0) atomicAdd(&gcnt[gcur], cnt);
}

__global__ __launch_bounds__(128) void pred_kernel(
    const float* __restrict__ sums, const int* __restrict__ gcnt,
    const float* __restrict__ pw, const float* __restrict__ pb, float* __restrict__ out) {
  __shared__ float red[2];
  int g = blockIdx.x, d = threadIdx.x;
  float c = fmaxf((float)gcnt[g], 1.f);
  float v = (sums[(size_t)g * 128 + d] / c) * pw[d];
  for (int o = 32; o > 0; o >>= 1) v += __shfl_down(v, o, 64);
  if ((d & 63) == 0) red[d >> 6] = v;
  __syncthreads();
  if (d == 0) out[g] = red[0] + red[1] + pb[0];
}

// ---------------- launch ----------------
extern "C" void kernel_launch(void* const* d_in, const int* in_sizes, int n_in,
                              void* d_out, int out_size, void* d_ws, size_t ws_size,
                              hipStream_t stream) {
  const float* x = (const float*)d_in[0];
  const float* pos = (const float*)d_in[1];
  const int* ei = (const int*)d_in[2];
  const float* ea = (const float*)d_in[3];
  const int* batch = (const int*)d_in[4];
  const float* lin_w = (const float*)d_in[5];
  const float* lin_b = (const float*)d_in[6];
  const float* mw1 = (const float*)d_in[7];
  const float* mb1 = (const float*)d_in[8];
  const float* mg = (const float*)d_in[9];
  const float* mbb = (const float*)d_in[10];
  const float* mm = (const float*)d_in[11];
  const float* mv = (const float*)d_in[12];
  const float* mw2 = (const float*)d_in[13];
  const float* mb2 = (const float*)d_in[14];
  const float* uw1 = (const float*)d_in[15];
  const float* ub1 = (const float*)d_in[16];
  const float* ug = (const float*)d_in[17];
  const float* ubb = (const float*)d_in[18];
  const float* um = (const float*)d_in[19];
  const float* uv = (const float*)d_in[20];
  const float* uw2 = (const float*)d_in[21];
  const float* ub2 = (const float*)d_in[22];
  const float* pw = (const float*)d_in[23];
  const float* pb = (const float*)d_in[24];
  float* out = (float*)d_out;

  const int Nn = in_sizes[0] / 11;
  const int Ee = in_sizes[3] / 4;
  const int* srcp = ei;        // edge_index[0] = source j
  const int* dstp = ei + Ee;   // edge_index[1] = target i

  char* wsb = (char*)d_ws;
  size_t off = 0;
  auto alloc = [&](size_t bytes) -> void* {
    void* p = wsb + off;
    off = (off + bytes + 255) & ~(size_t)255;
    return p;
  };
  float* h = (float*)alloc((size_t)Nn * 128 * 4);
  unsigned short* Pb = (unsigned short*)alloc((size_t)Nn * 128 * 2);
  unsigned short* Qb = (unsigned short*)alloc((size_t)Nn * 128 * 2);
  float* aggr = (float*)alloc((size_t)Nn * 128 * 4);
  int* dst_s = (int*)alloc((size_t)Ee * 4);
  int* src_s = (int*)alloc((size_t)Ee * 4);
  float* ea_s = (float*)alloc((size_t)Ee * 16);
  int* count = (int*)alloc((size_t)Nn * 4);
  int* cursor = (int*)alloc((size_t)Nn * 4);
  int* bsum = (int*)alloc((size_t)1024 * 4);
  const int nTiles = (Ee + 63) / 64;
  unsigned long long* masks = (unsigned long long*)alloc((size_t)nTiles * 8);
  unsigned short* mW2fT = (unsigned short*)alloc((size_t)4 * 128 * 128 * 2);
  unsigned short* uW2fT = (unsigned short*)alloc((size_t)4 * 128 * 128 * 2);
  unsigned short* W1abT = (unsigned short*)alloc((size_t)4 * 256 * 128 * 2);
  unsigned short* U1T = (unsigned short*)alloc((size_t)4 * 128 * 256 * 2);
  float* mB2f = (float*)alloc((size_t)4 * 128 * 4);
  float* uB2f = (float*)alloc((size_t)4 * 128 * 4);
  float* sums = (float*)alloc((size_t)out_size * 128 * 4);
  int* gcnt = (int*)alloc((size_t)out_size * 4);
  (void)ws_size; (void)n_in;

  fold_kernel<<<8, 128, 0, stream>>>(mw2, mb2, mg, mbb, mm, mv,
                                     uw2, ub2, ug, ubb, um, uv,
                                     mW2fT, mB2f, uW2fT, uB2f);
  transp_kernel<<<8, 256, 0, stream>>>(mw1, uw1, W1abT, U1T);
  lin_in_kernel<<<(Nn * 128 + 255) / 256, 256, 0, stream>>>(x, pos, lin_w, lin_b, h, Nn);

  hipMemsetAsync(count, 0, (size_t)Nn * 4, stream);
  hist_kernel<<<(Ee + 255) / 256, 256, 0, stream>>>(dstp, count, Ee);
  const int NB = (Nn + 1023) / 1024;
  scan1_kernel<<<NB, 1024, 0, stream>>>(count, cursor, bsum, Nn);
  scan2_kernel<<<1, 1024, 0, stream>>>(bsum, NB);
  scan3_kernel<<<NB, 1024, 0, stream>>>(cursor, bsum, Nn);
  scatter_kernel<<<(Ee + 255) / 256, 256, 0, stream>>>(srcp, dstp, ea, cursor,
                                                       dst_s, src_s, ea_s, Ee);
  mask_kernel<<<(nTiles + 3) / 4, 256, 0, stream>>>(dst_s, masks, Ee, nTiles);

  const int gN = (Nn + 63) / 64;
  pq_kernel<<<gN, 256, 0, stream>>>(h, W1abT, Pb, Qb, Nn);  // layer 0 P/Q
  for (int l = 0; l < 4; ++l) {
    hipMemsetAsync(aggr, 0, (size_t)Nn * 128 * 4, stream);
    edge_kernel<<<nTiles, 256, 0, stream>>>(
        Pb, Qb, ea_s, dst_s, src_s, masks,
        mw1 + (size_t)l * 260 * 128 + 256 * 128, mb1 + l * 128,
        mW2fT + (size_t)l * 16384, mB2f + l * 128, aggr, Ee);
    upd_kernel<<<gN, 256, 0, stream>>>(
        h, aggr, U1T + (size_t)l * 128 * 256, ub1 + l * 128,
        uW2fT + (size_t)l * 16384, uB2f + l * 128, Nn,
        (l < 3) ? (W1abT + (size_t)(l + 1) * 256 * 128) : nullptr, Pb, Qb);
  }

  hipMemsetAsync(sums, 0, (size_t)out_size * 128 * 4, stream);
  hipMemsetAsync(gcnt, 0, (size_t)out_size * 4, stream);
  pool_sum_kernel<<<(Nn + 255) / 256, 128, 0, stream>>>(h, batch, sums, gcnt, Nn);
  pred_kernel<<<out_size, 128, 0, stream>>>(sums, gcnt, pw, pb, out);
}

// Round 6
// 1939.091 us; speedup vs baseline: 3.4444x; 1.1242x over previous
//
#include <hip/hip_runtime.h>
#include <hip/hip_bf16.h>

// MPNN: N=100000 nodes, E=1600000 edges, D=128, L=4, G=64.
// All GEMM-shaped work on MFMA bf16 (fp32 accumulate), fp32 residual stream h.
//   prep: fold BN into W2 (both MLPs), transpose all B-matrices to [n][k] bf16,
//         counting-sort edges by dst, per-64-edge-tile segment-start bitmasks.
//   per layer:
//     edge_kernel (2 tiles/block, double-buffered pipeline):
//         t = relu(P[dst]+Q[src]+ea@W1c+b1) -> bf16 LDS (Tl[buf])
//         m = relu(t@W2f+b2f)   (MFMA) -> written back into Tl[buf]
//         mask-driven segmented reduce -> aggr (256-B-contiguous stores)
//     upd_kernel:  u1 = relu([h|aggr]@U1+ub1) (MFMA K=256) -> bf16 LDS overlay
//                  h += relu(u1@U2f+uB2f)     (MFMA K=128), in-place
//                  + fused next-layer P/Q = h_new @ W1ab (via LDS h_new tile)
// MFMA operand swap: acc = mfma(Wfrag, actFrag, acc) gives D[n][m]: lane holds
// (edge-row = lane&15, 4 consecutive out-cols = quad*4+reg) -> row-major stores.

#define EPSBN 1e-5f
#define TS 136   // bf16 elems per LDS row for 128-wide tiles (272 B = 17*16 B)
#define AS 264   // bf16 elems per LDS row for 256-wide tiles (528 B = 33*16 B)

typedef __bf16 bf16x8 __attribute__((ext_vector_type(8)));
typedef float floatx4 __attribute__((ext_vector_type(4)));

static __device__ __forceinline__ unsigned short f2b(float f) {
  union { float f; unsigned u; } v; v.f = f;
  unsigned u = v.u;
  return (unsigned short)((u + 0x7fffu + ((u >> 16) & 1u)) >> 16);  // RNE
}
static __device__ __forceinline__ unsigned pk2(float lo, float hi) {
  union { __hip_bfloat162 h; unsigned u; } v;
  v.h = __float22bfloat162_rn(make_float2(lo, hi));  // v_cvt_pk_bf16_f32
  return v.u;
}
static __device__ __forceinline__ float ubits(unsigned u) {
  union { unsigned u; float f; } v; v.u = u; return v.f;
}

// ---------------- fold BN into second linear, write transposed bf16 ----------------
__global__ __launch_bounds__(128) void fold_kernel(
    const float* __restrict__ mw2, const float* __restrict__ mb2,
    const float* __restrict__ mg, const float* __restrict__ mb,
    const float* __restrict__ mm, const float* __restrict__ mv,
    const float* __restrict__ uw2, const float* __restrict__ ub2,
    const float* __restrict__ ug, const float* __restrict__ ub,
    const float* __restrict__ um, const float* __restrict__ uv,
    unsigned short* __restrict__ mW2fT, float* __restrict__ mB2f,
    unsigned short* __restrict__ uW2fT, float* __restrict__ uB2f) {
  int l = blockIdx.x & 3;
  bool isu = blockIdx.x >= 4;
  const float* W2 = (isu ? uw2 : mw2) + (size_t)l * 128 * 128;
  const float* b2 = (isu ? ub2 : mb2) + l * 128;
  const float* gg = (isu ? ug : mg) + l * 128;
  const float* bb = (isu ? ub : mb) + l * 128;
  const float* mn = (isu ? um : mm) + l * 128;
  const float* vr = (isu ? uv : mv) + l * 128;
  unsigned short* WfT = (isu ? uW2fT : mW2fT) + (size_t)l * 128 * 128;
  float* Bf = (isu ? uB2f : mB2f) + l * 128;
  __shared__ float a[128], c[128];
  int d = threadIdx.x;
  float ad = gg[d] * rsqrtf(vr[d] + EPSBN);
  a[d] = ad;
  c[d] = bb[d] - mn[d] * ad;
  __syncthreads();
  float acc = b2[d];
  for (int k = 0; k < 128; ++k) {
    float w = W2[k * 128 + d];
    WfT[(size_t)d * 128 + k] = f2b(a[k] * w);  // [n][k] bf16
    acc = fmaf(c[k], w, acc);
  }
  Bf[d] = acc;
}

// ---------------- transpose W1ab / U1 to [n][k] bf16 ----------------
__global__ __launch_bounds__(256) void transp_kernel(
    const float* __restrict__ mw1, const float* __restrict__ uw1,
    unsigned short* __restrict__ W1abT, unsigned short* __restrict__ U1T) {
  int l = blockIdx.x & 3;
  bool isu = blockIdx.x >= 4;
  int tid = threadIdx.x;
  if (!isu) {
    const float* W = mw1 + (size_t)l * 260 * 128;
    unsigned short* T = W1abT + (size_t)l * 256 * 128;
    for (int i = tid; i < 256 * 128; i += 256) {
      int n = i >> 7, k = i & 127;
      float v = (n < 128) ? W[(size_t)k * 128 + n] : W[(size_t)(128 + k) * 128 + (n - 128)];
      T[i] = f2b(v);
    }
  } else {
    const float* W = uw1 + (size_t)l * 256 * 128;
    unsigned short* T = U1T + (size_t)l * 128 * 256;
    for (int i = tid; i < 128 * 256; i += 256) {
      int n = i >> 8, k = i & 255;
      T[i] = f2b(W[(size_t)k * 128 + n]);
    }
  }
}

// ---------------- input projection ----------------
__global__ __launch_bounds__(256) void lin_in_kernel(
    const float* __restrict__ x, const float* __restrict__ pos,
    const float* __restrict__ W, const float* __restrict__ b,
    float* __restrict__ h, int Nn) {
  int gi = blockIdx.x * 256 + threadIdx.x;
  if (gi >= Nn * 128) return;
  int n = gi >> 7, d = gi & 127;
  float acc = b[d];
#pragma unroll
  for (int j = 0; j < 11; ++j) acc = fmaf(x[(size_t)n * 11 + j], W[j * 128 + d], acc);
#pragma unroll
  for (int j = 0; j < 3; ++j) acc = fmaf(pos[(size_t)n * 3 + j], W[(11 + j) * 128 + d], acc);
  h[gi] = acc;
}

// ---------------- counting sort of edges by dst ----------------
__global__ __launch_bounds__(256) void hist_kernel(const int* __restrict__ dst, int* __restrict__ count, int Ee) {
  int i = blockIdx.x * 256 + threadIdx.x;
  if (i < Ee) atomicAdd(&count[dst[i]], 1);
}

// 3-kernel parallel exclusive scan over count[n] -> cursor[n]
__global__ __launch_bounds__(1024) void scan1_kernel(
    const int* __restrict__ count, int* __restrict__ cursor, int* __restrict__ bsum, int n) {
  __shared__ int buf[1024];
  int i = blockIdx.x * 1024 + threadIdx.x;
  int v = (i < n) ? count[i] : 0;
  buf[threadIdx.x] = v;
  __syncthreads();
  for (int off = 1; off < 1024; off <<= 1) {
    int t = (threadIdx.x >= off) ? buf[threadIdx.x - off] : 0;
    __syncthreads();
    buf[threadIdx.x] += t;
    __syncthreads();
  }
  if (i < n) cursor[i] = buf[threadIdx.x] - v;  // exclusive within block
  if (threadIdx.x == 1023) bsum[blockIdx.x] = buf[1023];
}
__global__ __launch_bounds__(1024) void scan2_kernel(int* __restrict__ bsum, int nb) {
  __shared__ int buf[1024];
  int v = (threadIdx.x < nb) ? bsum[threadIdx.x] : 0;
  buf[threadIdx.x] = v;
  __syncthreads();
  for (int off = 1; off < 1024; off <<= 1) {
    int t = (threadIdx.x >= off) ? buf[threadIdx.x - off] : 0;
    __syncthreads();
    buf[threadIdx.x] += t;
    __syncthreads();
  }
  if (threadIdx.x < nb) bsum[threadIdx.x] = buf[threadIdx.x] - v;  // exclusive
}
__global__ __launch_bounds__(1024) void scan3_kernel(
    int* __restrict__ cursor, const int* __restrict__ bsum, int n) {
  int i = blockIdx.x * 1024 + threadIdx.x;
  if (i < n) cursor[i] += bsum[blockIdx.x];
}

__global__ __launch_bounds__(256) void scatter_kernel(
    const int* __restrict__ src, const int* __restrict__ dst, const float* __restrict__ ea,
    int* __restrict__ cursor, int* __restrict__ dst_s, int* __restrict__ src_s,
    float* __restrict__ ea_s, int Ee) {
  int e = blockIdx.x * 256 + threadIdx.x;
  if (e >= Ee) return;
  int dn = dst[e];
  int pos = atomicAdd(&cursor[dn], 1);
  dst_s[pos] = dn;
  src_s[pos] = src[e];
  *(float4*)(ea_s + (size_t)pos * 4) = *(const float4*)(ea + (size_t)e * 4);
}

// per-64-edge-tile segment-start bitmask (bit i = edge 64T+i starts a run)
__global__ __launch_bounds__(256) void mask_kernel(
    const int* __restrict__ dst_s, unsigned long long* __restrict__ masks, int Ee, int nt) {
  int tile = blockIdx.x * 4 + (threadIdx.x >> 6);
  int lane = threadIdx.x & 63;
  if (tile >= nt) return;
  int e = tile * 64 + lane;
  bool start;
  if (e >= Ee || lane == 0) start = true;
  else start = (dst_s[e] != dst_s[e - 1]);
  unsigned long long m = __ballot(start);
  if (lane == 0) masks[tile] = m;
}

// ---------------- pq_kernel: P = h@W1a, Q = h@W1b (bf16 out, MFMA) ----------------
// (standalone for layer 0; later layers fused into upd_kernel)
__global__ __launch_bounds__(256) void pq_kernel(
    const float* __restrict__ h, const unsigned short* __restrict__ W1abT,
    unsigned short* __restrict__ P, unsigned short* __restrict__ Q, int Nn) {
  __shared__ unsigned short hs[64 * TS];
  const int tid = threadIdx.x;
  const int row0 = blockIdx.x * 64;
#pragma unroll
  for (int i = 0; i < 8; ++i) {
    int idx = tid + i * 256;
    int r = idx >> 5, c4 = (idx & 31) << 2;
    float4 v = make_float4(0.f, 0.f, 0.f, 0.f);
    if (row0 + r < Nn) v = *(const float4*)(h + (size_t)(row0 + r) * 128 + c4);
    *(uint2*)&hs[r * TS + c4] = make_uint2(pk2(v.x, v.y), pk2(v.z, v.w));
  }
  __syncthreads();
  const int lane = tid & 63, wv = tid >> 6;
  const int m16 = lane & 15, quad = lane >> 4;
  floatx4 acc[4][4];
#pragma unroll
  for (int mt = 0; mt < 4; ++mt)
#pragma unroll
    for (int nt = 0; nt < 4; ++nt) acc[mt][nt] = (floatx4)(0.0f);
  const __bf16* WT = (const __bf16*)W1abT;
  const __bf16* TlB = (const __bf16*)hs;
#pragma unroll
  for (int kb = 0; kb < 4; ++kb) {
    bf16x8 a[4], w[4];
#pragma unroll
    for (int mt = 0; mt < 4; ++mt)
      a[mt] = *(const bf16x8*)(TlB + (16 * mt + m16) * TS + kb * 32 + quad * 8);
#pragma unroll
    for (int nt = 0; nt < 4; ++nt)
      w[nt] = *(const bf16x8*)(WT + (size_t)(64 * wv + 16 * nt + m16) * 128 + kb * 32 + quad * 8);
#pragma unroll
    for (int mt = 0; mt < 4; ++mt)
#pragma unroll
      for (int nt = 0; nt < 4; ++nt)
        acc[mt][nt] = __builtin_amdgcn_mfma_f32_16x16x32_bf16(w[nt], a[mt], acc[mt][nt], 0, 0, 0);
  }
#pragma unroll
  for (int mt = 0; mt < 4; ++mt) {
    int row = row0 + 16 * mt + m16;
    if (row >= Nn) continue;
#pragma unroll
    for (int nt = 0; nt < 4; ++nt) {
      int n0 = 64 * wv + 16 * nt + 4 * quad;
      floatx4 A = acc[mt][nt];
      uint2 o = make_uint2(pk2(A[0], A[1]), pk2(A[2], A[3]));
      if (n0 < 128) *(uint2*)(P + (size_t)row * 128 + n0) = o;
      else *(uint2*)(Q + (size_t)row * 128 + (n0 - 128)) = o;
    }
  }
}

// ---------------- edge kernel helpers ----------------
static __device__ __forceinline__ void gather_pq(
    const unsigned short* __restrict__ P, const unsigned short* __restrict__ Q,
    const int* __restrict__ sdstBase, const int* __restrict__ ssrcBase,
    int rw, int c0, uint4* pv, uint4* qv) {
#pragma unroll
  for (int p = 0; p < 4; ++p) {
    int slot = 16 * p + rw;
    int dn = sdstBase[slot];
    int dna = dn < 0 ? 0 : dn;
    int sna = ssrcBase[slot];
    pv[p] = *(const uint4*)(P + (size_t)dna * 128 + c0);
    qv[p] = *(const uint4*)(Q + (size_t)sna * 128 + c0);
  }
}

static __device__ __forceinline__ void build_T(
    unsigned short* __restrict__ TlBuf,
    const uint4* pv, const uint4* qv,
    const int* __restrict__ sdstBase, const float* __restrict__ seaBase,
    const float wc[4][8], const float b1r[8], int rw, int c0) {
#pragma unroll
  for (int p = 0; p < 4; ++p) {
    int row = 16 * p + rw;
    int dn = sdstBase[row];
    uint4 out = make_uint4(0u, 0u, 0u, 0u);
    if (dn >= 0) {
      float e0f = seaBase[row * 4 + 0], e1f = seaBase[row * 4 + 1];
      float e2f = seaBase[row * 4 + 2], e3f = seaBase[row * 4 + 3];
      unsigned pu[4] = {pv[p].x, pv[p].y, pv[p].z, pv[p].w};
      unsigned qu[4] = {qv[p].x, qv[p].y, qv[p].z, qv[p].w};
      unsigned ou[4];
#pragma unroll
      for (int g = 0; g < 4; ++g) {
        float plo = ubits(pu[g] << 16), phi = ubits(pu[g] & 0xffff0000u);
        float qlo = ubits(qu[g] << 16), qhi = ubits(qu[g] & 0xffff0000u);
        int j0 = 2 * g, j1 = 2 * g + 1;
        float t0 = plo + qlo + b1r[j0];
        float t1 = phi + qhi + b1r[j1];
        t0 = fmaf(e0f, wc[0][j0], fmaf(e1f, wc[1][j0], fmaf(e2f, wc[2][j0], fmaf(e3f, wc[3][j0], t0))));
        t1 = fmaf(e0f, wc[0][j1], fmaf(e1f, wc[1][j1], fmaf(e2f, wc[2][j1], fmaf(e3f, wc[3][j1], t1))));
        ou[g] = pk2(fmaxf(t0, 0.f), fmaxf(t1, 0.f));
      }
      out = make_uint4(ou[0], ou[1], ou[2], ou[3]);
    }
    *(uint4*)&TlBuf[row * TS + c0] = out;
  }
}

static __device__ __forceinline__ void mfma_B(
    const unsigned short* __restrict__ TlBuf, const __bf16* __restrict__ WT,
    int m16, int quad, int wv, floatx4 acc[4][2]) {
#pragma unroll
  for (int mt = 0; mt < 4; ++mt) { acc[mt][0] = (floatx4)(0.0f); acc[mt][1] = (floatx4)(0.0f); }
  const __bf16* TlB = (const __bf16*)TlBuf;
#pragma unroll
  for (int kb = 0; kb < 4; ++kb) {
    bf16x8 w0 = *(const bf16x8*)(WT + (size_t)(32 * wv + m16) * 128 + kb * 32 + quad * 8);
    bf16x8 w1 = *(const bf16x8*)(WT + (size_t)(32 * wv + 16 + m16) * 128 + kb * 32 + quad * 8);
    bf16x8 a[4];
#pragma unroll
    for (int mt = 0; mt < 4; ++mt)
      a[mt] = *(const bf16x8*)(TlB + (16 * mt + m16) * TS + kb * 32 + quad * 8);
#pragma unroll
    for (int mt = 0; mt < 4; ++mt) {
      acc[mt][0] = __builtin_amdgcn_mfma_f32_16x16x32_bf16(w0, a[mt], acc[mt][0], 0, 0, 0);
      acc[mt][1] = __builtin_amdgcn_mfma_f32_16x16x32_bf16(w1, a[mt], acc[mt][1], 0, 0, 0);
    }
  }
}

static __device__ __forceinline__ void epi_m(
    unsigned short* __restrict__ TlBuf, floatx4 acc[4][2],
    const float* __restrict__ B2f, int m16, int quad, int wv) {
  int n0 = 32 * wv + 4 * quad;
  float4 bv0 = *(const float4*)(B2f + n0);
  float4 bv1 = *(const float4*)(B2f + n0 + 16);
#pragma unroll
  for (int mt = 0; mt < 4; ++mt) {
    int row = 16 * mt + m16;
    floatx4 A0 = acc[mt][0], A1 = acc[mt][1];
    *(uint2*)&TlBuf[row * TS + n0] =
        make_uint2(pk2(fmaxf(A0[0] + bv0.x, 0.f), fmaxf(A0[1] + bv0.y, 0.f)),
                   pk2(fmaxf(A0[2] + bv0.z, 0.f), fmaxf(A0[3] + bv0.w, 0.f)));
    *(uint2*)&TlBuf[row * TS + n0 + 16] =
        make_uint2(pk2(fmaxf(A1[0] + bv1.x, 0.f), fmaxf(A1[1] + bv1.y, 0.f)),
                   pk2(fmaxf(A1[2] + bv1.z, 0.f), fmaxf(A1[3] + bv1.w, 0.f)));
  }
}

// mask-driven segmented reduce; thread covers cols c4..c4+3 and 64+c4..64+c4+3
// -> each store instruction across the 16 participating consecutive lanes is
// 256 B contiguous (write-coalescing fix).
static __device__ __forceinline__ void seg_reduce(
    const unsigned short* __restrict__ TlBuf, const int* __restrict__ sdstBase,
    unsigned long long mask, float* __restrict__ aggr, int tid) {
  const int c4 = (tid & 15) << 2;
  const int st = tid >> 4;
  const int dfirst = sdstBase[0], dlast = sdstBase[63];
  for (int s = st; s < 64; s += 16) {
    if (!(mask & (1ull << s))) continue;
    int dn = sdstBase[s];
    if (dn < 0) continue;
    int end;
    if (s >= 63) end = 64;
    else {
      unsigned long long m2 = mask >> (s + 1);
      end = m2 ? (s + 1 + (int)__builtin_ctzll(m2)) : 64;
    }
    float a0 = 0.f, a1 = 0.f, a2 = 0.f, a3 = 0.f, a4 = 0.f, a5 = 0.f, a6 = 0.f, a7 = 0.f;
    for (int e = s; e < end; ++e) {
      uint2 v1 = *(const uint2*)&TlBuf[e * TS + c4];
      uint2 v2 = *(const uint2*)&TlBuf[e * TS + 64 + c4];
      a0 += ubits(v1.x << 16); a1 += ubits(v1.x & 0xffff0000u);
      a2 += ubits(v1.y << 16); a3 += ubits(v1.y & 0xffff0000u);
      a4 += ubits(v2.x << 16); a5 += ubits(v2.x & 0xffff0000u);
      a6 += ubits(v2.y << 16); a7 += ubits(v2.y & 0xffff0000u);
    }
    float* ap = aggr + (size_t)dn * 128 + c4;
    if (dn == dfirst || dn == dlast) {
      atomicAdd(ap + 0, a0); atomicAdd(ap + 1, a1);
      atomicAdd(ap + 2, a2); atomicAdd(ap + 3, a3);
      atomicAdd(ap + 64, a4); atomicAdd(ap + 65, a5);
      atomicAdd(ap + 66, a6); atomicAdd(ap + 67, a7);
    } else {
      *(float4*)ap = make_float4(a0, a1, a2, a3);
      *(float4*)(ap + 64) = make_float4(a4, a5, a6, a7);
    }
  }
}

// ---------------- edge message kernel: 2 tiles/block, pipelined ----------------
__global__ __launch_bounds__(256, 3) void edge_kernel(
    const unsigned short* __restrict__ P, const unsigned short* __restrict__ Q,
    const float* __restrict__ ea_s, const int* __restrict__ dst_s, const int* __restrict__ src_s,
    const unsigned long long* __restrict__ masks,
    const float* __restrict__ W1c, const float* __restrict__ b1,
    const unsigned short* __restrict__ W2fT, const float* __restrict__ B2f,
    float* __restrict__ aggr, int Ee, int nT) {
  __shared__ unsigned short Tl[2][64 * TS];
  __shared__ float sea[128 * 4];
  __shared__ int sdst[128], ssrc[128];
  const int tid = threadIdx.x;
  const int t0 = blockIdx.x * 2, t1 = t0 + 1;
  const int e0 = t0 * 64;
  const bool has1 = (t1 < nT);
  const unsigned long long mask0 = masks[t0];
  const unsigned long long mask1 = has1 ? masks[t1] : 0ull;
  if (tid < 128) {
    int e = e0 + tid;
    bool ok = e < Ee;
    sdst[tid] = ok ? dst_s[e] : -1;
    ssrc[tid] = ok ? src_s[e] : 0;
    float4 ev = ok ? *(const float4*)(ea_s + (size_t)e * 4) : make_float4(0.f, 0.f, 0.f, 0.f);
    *(float4*)&sea[tid * 4] = ev;
  }
  // per-thread W1c slice: cols c0..c0+7
  const int rw = tid >> 4, c0 = (tid & 15) << 3;
  float wc[4][8], b1r[8];
#pragma unroll
  for (int r = 0; r < 4; ++r) {
    *(float4*)&wc[r][0] = *(const float4*)(W1c + r * 128 + c0);
    *(float4*)&wc[r][4] = *(const float4*)(W1c + r * 128 + c0 + 4);
  }
  *(float4*)&b1r[0] = *(const float4*)(b1 + c0);
  *(float4*)&b1r[4] = *(const float4*)(b1 + c0 + 4);
  __syncthreads();

  const int lane = tid & 63, wv = tid >> 6;
  const int m16 = lane & 15, quad = lane >> 4;
  const __bf16* WT = (const __bf16*)W2fT;

  // --- pipeline ---
  uint4 pv[4], qv[4], pv1[4], qv1[4];
  gather_pq(P, Q, sdst, ssrc, rw, c0, pv, qv);                 // tile0 gathers
  build_T(Tl[0], pv, qv, sdst, sea, wc, b1r, rw, c0);          // T0 -> Tl[0]
  if (has1) gather_pq(P, Q, sdst + 64, ssrc + 64, rw, c0, pv1, qv1);  // tile1 gathers in flight
  __syncthreads();                                             // Tl[0] ready

  floatx4 acc[4][2];
  mfma_B(Tl[0], WT, m16, quad, wv, acc);                       // B0 (reads Tl[0])
  if (has1) build_T(Tl[1], pv1, qv1, sdst + 64, sea + 256, wc, b1r, rw, c0);  // T1 -> Tl[1]
  __syncthreads();                                             // B0 reads done; Tl[1] ready

  epi_m(Tl[0], acc, B2f, m16, quad, wv);                       // m0 -> Tl[0]
  floatx4 acc1[4][2];
  if (has1) mfma_B(Tl[1], WT, m16, quad, wv, acc1);            // B1 (reads Tl[1])
  __syncthreads();                                             // m0 ready; B1 reads done

  seg_reduce(Tl[0], sdst, mask0, aggr, tid);                   // C0
  if (has1) {
    epi_m(Tl[1], acc1, B2f, m16, quad, wv);                    // m1 -> Tl[1]
    __syncthreads();                                           // m1 ready
    seg_reduce(Tl[1], sdst + 64, mask1, aggr, tid);            // C1
  }
}

// ---------------- fused update MLP (+ next-layer P/Q), MFMA, in-place h ----------------
__global__ __launch_bounds__(256) void upd_kernel(
    float* __restrict__ h, const float* __restrict__ aggr,
    const unsigned short* __restrict__ U1T, const float* __restrict__ ub1,
    const unsigned short* __restrict__ uW2fT, const float* __restrict__ uB2f, int Nn,
    const unsigned short* __restrict__ W1abT_next,
    unsigned short* __restrict__ P, unsigned short* __restrict__ Q) {
  __shared__ unsigned short as_[64 * AS];  // [h|aggr]; u1 overlay; then h_new overlay
  const int tid = threadIdx.x;
  const int row0 = blockIdx.x * 64;
#pragma unroll
  for (int i = 0; i < 8; ++i) {
    int idx = tid + i * 256;
    int r = idx >> 5, c4 = (idx & 31) << 2;
    float4 v = make_float4(0.f, 0.f, 0.f, 0.f);
    if (row0 + r < Nn) v = *(const float4*)(h + (size_t)(row0 + r) * 128 + c4);
    *(uint2*)&as_[r * AS + c4] = make_uint2(pk2(v.x, v.y), pk2(v.z, v.w));
  }
#pragma unroll
  for (int i = 0; i < 8; ++i) {
    int idx = tid + i * 256;
    int r = idx >> 5, c4 = (idx & 31) << 2;
    float4 v = make_float4(0.f, 0.f, 0.f, 0.f);
    if (row0 + r < Nn) v = *(const float4*)(aggr + (size_t)(row0 + r) * 128 + c4);
    *(uint2*)&as_[r * AS + 128 + c4] = make_uint2(pk2(v.x, v.y), pk2(v.z, v.w));
  }
  __syncthreads();
  const int lane = tid & 63, wv = tid >> 6;
  const int m16 = lane & 15, quad = lane >> 4;
  const __bf16* asB = (const __bf16*)as_;
  unsigned short* u1s = as_;  // overlay (TS stride)
  // pass 1: u1 = relu([h|aggr]@U1 + ub1), K=256
  {
    floatx4 acc[4][2];
#pragma unroll
    for (int mt = 0; mt < 4; ++mt) { acc[mt][0] = (floatx4)(0.0f); acc[mt][1] = (floatx4)(0.0f); }
    const __bf16* WT = (const __bf16*)U1T;
#pragma unroll
    for (int kb = 0; kb < 8; ++kb) {
      bf16x8 w0 = *(const bf16x8*)(WT + (size_t)(32 * wv + m16) * 256 + kb * 32 + quad * 8);
      bf16x8 w1 = *(const bf16x8*)(WT + (size_t)(32 * wv + 16 + m16) * 256 + kb * 32 + quad * 8);
      bf16x8 a[4];
#pragma unroll
      for (int mt = 0; mt < 4; ++mt)
        a[mt] = *(const bf16x8*)(asB + (16 * mt + m16) * AS + kb * 32 + quad * 8);
#pragma unroll
      for (int mt = 0; mt < 4; ++mt) {
        acc[mt][0] = __builtin_amdgcn_mfma_f32_16x16x32_bf16(w0, a[mt], acc[mt][0], 0, 0, 0);
        acc[mt][1] = __builtin_amdgcn_mfma_f32_16x16x32_bf16(w1, a[mt], acc[mt][1], 0, 0, 0);
      }
    }
    __syncthreads();  // pass-1 reads of as_ complete -> safe to overlay u1
    int n0 = 32 * wv + 4 * quad;
    float4 bv0 = *(const float4*)(ub1 + n0);
    float4 bv1 = *(const float4*)(ub1 + n0 + 16);
#pragma unroll
    for (int mt = 0; mt < 4; ++mt) {
      int row = 16 * mt + m16;
      floatx4 A0 = acc[mt][0], A1 = acc[mt][1];
      *(uint2*)&u1s[row * TS + n0] =
          make_uint2(pk2(fmaxf(A0[0] + bv0.x, 0.f), fmaxf(A0[1] + bv0.y, 0.f)),
                     pk2(fmaxf(A0[2] + bv0.z, 0.f), fmaxf(A0[3] + bv0.w, 0.f)));
      *(uint2*)&u1s[row * TS + n0 + 16] =
          make_uint2(pk2(fmaxf(A1[0] + bv1.x, 0.f), fmaxf(A1[1] + bv1.y, 0.f)),
                     pk2(fmaxf(A1[2] + bv1.z, 0.f), fmaxf(A1[3] + bv1.w, 0.f)));
    }
  }
  __syncthreads();
  // pass 2: h_new = h + relu(u1@U2f + uB2f), K=128; write global + LDS bf16
  {
    floatx4 acc[4][2];
#pragma unroll
    for (int mt = 0; mt < 4; ++mt) { acc[mt][0] = (floatx4)(0.0f); acc[mt][1] = (floatx4)(0.0f); }
    const __bf16* WT = (const __bf16*)uW2fT;
    const __bf16* u1B = (const __bf16*)u1s;
#pragma unroll
    for (int kb = 0; kb < 4; ++kb) {
      bf16x8 w0 = *(const bf16x8*)(WT + (size_t)(32 * wv + m16) * 128 + kb * 32 + quad * 8);
      bf16x8 w1 = *(const bf16x8*)(WT + (size_t)(32 * wv + 16 + m16) * 128 + kb * 32 + quad * 8);
      bf16x8 a[4];
#pragma unroll
      for (int mt = 0; mt < 4; ++mt)
        a[mt] = *(const bf16x8*)(u1B + (16 * mt + m16) * TS + kb * 32 + quad * 8);
#pragma unroll
      for (int mt = 0; mt < 4; ++mt) {
        acc[mt][0] = __builtin_amdgcn_mfma_f32_16x16x32_bf16(w0, a[mt], acc[mt][0], 0, 0, 0);
        acc[mt][1] = __builtin_amdgcn_mfma_f32_16x16x32_bf16(w1, a[mt], acc[mt][1], 0, 0, 0);
      }
    }
    __syncthreads();  // pass-2 reads of u1s complete -> safe to overlay h_new
    int n0 = 32 * wv + 4 * quad;
    float4 bv0 = *(const float4*)(uB2f + n0);
    float4 bv1 = *(const float4*)(uB2f + n0 + 16);
#pragma unroll
    for (int mt = 0; mt < 4; ++mt) {
      int rloc = 16 * mt + m16;
      int row = row0 + rloc;
      floatx4 A0 = acc[mt][0], A1 = acc[mt][1];
      if (row < Nn) {
        float* hp0 = h + (size_t)row * 128 + n0;
        float4 hv0 = *(float4*)hp0;
        float4 o0 = make_float4(hv0.x + fmaxf(A0[0] + bv0.x, 0.f), hv0.y + fmaxf(A0[1] + bv0.y, 0.f),
                                hv0.z + fmaxf(A0[2] + bv0.z, 0.f), hv0.w + fmaxf(A0[3] + bv0.w, 0.f));
        *(float4*)hp0 = o0;
        float* hp1 = hp0 + 16;
        float4 hv1 = *(float4*)hp1;
        float4 o1 = make_float4(hv1.x + fmaxf(A1[0] + bv1.x, 0.f), hv1.y + fmaxf(A1[1] + bv1.y, 0.f),
                                hv1.z + fmaxf(A1[2] + bv1.z, 0.f), hv1.w + fmaxf(A1[3] + bv1.w, 0.f));
        *(float4*)hp1 = o1;
        if (W1abT_next) {
          *(uint2*)&u1s[rloc * TS + n0] = make_uint2(pk2(o0.x, o0.y), pk2(o0.z, o0.w));
          *(uint2*)&u1s[rloc * TS + n0 + 16] = make_uint2(pk2(o1.x, o1.y), pk2(o1.z, o1.w));
        }
      } else if (W1abT_next) {
        *(uint2*)&u1s[rloc * TS + n0] = make_uint2(0u, 0u);
        *(uint2*)&u1s[rloc * TS + n0 + 16] = make_uint2(0u, 0u);
      }
    }
  }
  // fused next-layer P/Q from h_new tile in LDS
  if (W1abT_next) {
    __syncthreads();
    floatx4 pacc[4][4];
#pragma unroll
    for (int mt = 0; mt < 4; ++mt)
#pragma unroll
      for (int nt = 0; nt < 4; ++nt) pacc[mt][nt] = (floatx4)(0.0f);
    const __bf16* WT = (const __bf16*)W1abT_next;
    const __bf16* hB = (const __bf16*)u1s;
#pragma unroll
    for (int kb = 0; kb < 4; ++kb) {
      bf16x8 a[4], w[4];
#pragma unroll
      for (int mt = 0; mt < 4; ++mt)
        a[mt] = *(const bf16x8*)(hB + (16 * mt + m16) * TS + kb * 32 + quad * 8);
#pragma unroll
      for (int nt = 0; nt < 4; ++nt)
        w[nt] = *(const bf16x8*)(WT + (size_t)(64 * wv + 16 * nt + m16) * 128 + kb * 32 + quad * 8);
#pragma unroll
      for (int mt = 0; mt < 4; ++mt)
#pragma unroll
        for (int nt = 0; nt < 4; ++nt)
          pacc[mt][nt] = __builtin_amdgcn_mfma_f32_16x16x32_bf16(w[nt], a[mt], pacc[mt][nt], 0, 0, 0);
    }
#pragma unroll
    for (int mt = 0; mt < 4; ++mt) {
      int row = row0 + 16 * mt + m16;
      if (row >= Nn) continue;
#pragma unroll
      for (int nt = 0; nt < 4; ++nt) {
        int n0 = 64 * wv + 16 * nt + 4 * quad;
        floatx4 A = pacc[mt][nt];
        uint2 o = make_uint2(pk2(A[0], A[1]), pk2(A[2], A[3]));
        if (n0 < 128) *(uint2*)(P + (size_t)row * 128 + n0) = o;
        else *(uint2*)(Q + (size_t)row * 128 + (n0 - 128)) = o;
      }
    }
  }
}

// ---------------- pooling ----------------
__global__ __launch_bounds__(128) void pool_sum_kernel(
    const float* __restrict__ h, const int* __restrict__ batch,
    float* __restrict__ sums, int* __restrict__ gcnt, int Nn) {
  int n0 = blockIdx.x * 256;
  if (n0 >= Nn) return;
  int nend = min(n0 + 256, Nn);
  int d = threadIdx.x;
  int gcur = batch[n0];
  float run = 0.f;
  int cnt = 0;
  for (int n = n0; n < nend; ++n) {
    int g = batch[n];
    if (g != gcur) {
      atomicAdd(&sums[(size_t)gcur * 128 + d], run);
      if (d == 0) atomicAdd(&gcnt[gcur], cnt);
      run = 0.f; cnt = 0; gcur = g;
    }
    run += h[(size_t)n * 128 + d];
    cnt += 1;
  }
  atomicAdd(&sums[(size_t)gcur * 128 + d], run);
  if (d == 0) atomicAdd(&gcnt[gcur], cnt);
}

__global__ __launch_bounds__(128) void pred_kernel(
    const float* __restrict__ sums, const int* __restrict__ gcnt,
    const float* __restrict__ pw, const float* __restrict__ pb, float* __restrict__ out) {
  __shared__ float red[2];
  int g = blockIdx.x, d = threadIdx.x;
  float c = fmaxf((float)gcnt[g], 1.f);
  float v = (sums[(size_t)g * 128 + d] / c) * pw[d];
  for (int o = 32; o > 0; o >>= 1) v += __shfl_down(v, o, 64);
  if ((d & 63) == 0) red[d >> 6] = v;
  __syncthreads();
  if (d == 0) out[g] = red[0] + red[1] + pb[0];
}

// ---------------- launch ----------------
extern "C" void kernel_launch(void* const* d_in, const int* in_sizes, int n_in,
                              void* d_out, int out_size, void* d_ws, size_t ws_size,
                              hipStream_t stream) {
  const float* x = (const float*)d_in[0];
  const float* pos = (const float*)d_in[1];
  const int* ei = (const int*)d_in[2];
  const float* ea = (const float*)d_in[3];
  const int* batch = (const int*)d_in[4];
  const float* lin_w = (const float*)d_in[5];
  const float* lin_b = (const float*)d_in[6];
  const float* mw1 = (const float*)d_in[7];
  const float* mb1 = (const float*)d_in[8];
  const float* mg = (const float*)d_in[9];
  const float* mbb = (const float*)d_in[10];
  const float* mm = (const float*)d_in[11];
  const float* mv = (const float*)d_in[12];
  const float* mw2 = (const float*)d_in[13];
  const float* mb2 = (const float*)d_in[14];
  const float* uw1 = (const float*)d_in[15];
  const float* ub1 = (const float*)d_in[16];
  const float* ug = (const float*)d_in[17];
  const float* ubb = (const float*)d_in[18];
  const float* um = (const float*)d_in[19];
  const float* uv = (const float*)d_in[20];
  const float* uw2 = (const float*)d_in[21];
  const float* ub2 = (const float*)d_in[22];
  const float* pw = (const float*)d_in[23];
  const float* pb = (const float*)d_in[24];
  float* out = (float*)d_out;

  const int Nn = in_sizes[0] / 11;
  const int Ee = in_sizes[3] / 4;
  const int* srcp = ei;        // edge_index[0] = source j
  const int* dstp = ei + Ee;   // edge_index[1] = target i

  char* wsb = (char*)d_ws;
  size_t off = 0;
  auto alloc = [&](size_t bytes) -> void* {
    void* p = wsb + off;
    off = (off + bytes + 255) & ~(size_t)255;
    return p;
  };
  float* h = (float*)alloc((size_t)Nn * 128 * 4);
  unsigned short* Pb = (unsigned short*)alloc((size_t)Nn * 128 * 2);
  unsigned short* Qb = (unsigned short*)alloc((size_t)Nn * 128 * 2);
  float* aggr = (float*)alloc((size_t)Nn * 128 * 4);
  int* dst_s = (int*)alloc((size_t)Ee * 4);
  int* src_s = (int*)alloc((size_t)Ee * 4);
  float* ea_s = (float*)alloc((size_t)Ee * 16);
  int* count = (int*)alloc((size_t)Nn * 4);
  int* cursor = (int*)alloc((size_t)Nn * 4);
  int* bsum = (int*)alloc((size_t)1024 * 4);
  const int nTiles = (Ee + 63) / 64;
  unsigned long long* masks = (unsigned long long*)alloc((size_t)nTiles * 8);
  unsigned short* mW2fT = (unsigned short*)alloc((size_t)4 * 128 * 128 * 2);
  unsigned short* uW2fT = (unsigned short*)alloc((size_t)4 * 128 * 128 * 2);
  unsigned short* W1abT = (unsigned short*)alloc((size_t)4 * 256 * 128 * 2);
  unsigned short* U1T = (unsigned short*)alloc((size_t)4 * 128 * 256 * 2);
  float* mB2f = (float*)alloc((size_t)4 * 128 * 4);
  float* uB2f = (float*)alloc((size_t)4 * 128 * 4);
  float* sums = (float*)alloc((size_t)out_size * 128 * 4);
  int* gcnt = (int*)alloc((size_t)out_size * 4);
  (void)ws_size; (void)n_in;

  fold_kernel<<<8, 128, 0, stream>>>(mw2, mb2, mg, mbb, mm, mv,
                                     uw2, ub2, ug, ubb, um, uv,
                                     mW2fT, mB2f, uW2fT, uB2f);
  transp_kernel<<<8, 256, 0, stream>>>(mw1, uw1, W1abT, U1T);
  lin_in_kernel<<<(Nn * 128 + 255) / 256, 256, 0, stream>>>(x, pos, lin_w, lin_b, h, Nn);

  hipMemsetAsync(count, 0, (size_t)Nn * 4, stream);
  hist_kernel<<<(Ee + 255) / 256, 256, 0, stream>>>(dstp, count, Ee);
  const int NB = (Nn + 1023) / 1024;
  scan1_kernel<<<NB, 1024, 0, stream>>>(count, cursor, bsum, Nn);
  scan2_kernel<<<1, 1024, 0, stream>>>(bsum, NB);
  scan3_kernel<<<NB, 1024, 0, stream>>>(cursor, bsum, Nn);
  scatter_kernel<<<(Ee + 255) / 256, 256, 0, stream>>>(srcp, dstp, ea, cursor,
                                                       dst_s, src_s, ea_s, Ee);
  mask_kernel<<<(nTiles + 3) / 4, 256, 0, stream>>>(dst_s, masks, Ee, nTiles);

  const int gN = (Nn + 63) / 64;
  pq_kernel<<<gN, 256, 0, stream>>>(h, W1abT, Pb, Qb, Nn);  // layer 0 P/Q
  for (int l = 0; l < 4; ++l) {
    hipMemsetAsync(aggr, 0, (size_t)Nn * 128 * 4, stream);
    edge_kernel<<<(nTiles + 1) / 2, 256, 0, stream>>>(
        Pb, Qb, ea_s, dst_s, src_s, masks,
        mw1 + (size_t)l * 260 * 128 + 256 * 128, mb1 + l * 128,
        mW2fT + (size_t)l * 16384, mB2f + l * 128, aggr, Ee, nTiles);
    upd_kernel<<<gN, 256, 0, stream>>>(
        h, aggr, U1T + (size_t)l * 128 * 256, ub1 + l * 128,
        uW2fT + (size_t)l * 16384, uB2f + l * 128, Nn,
        (l < 3) ? (W1abT + (size_t)(l + 1) * 256 * 128) : nullptr, Pb, Qb);
  }

  hipMemsetAsync(sums, 0, (size_t)out_size * 128 * 4, stream);
  hipMemsetAsync(gcnt, 0, (size_t)out_size * 4, stream);
  pool_sum_kernel<<<(Nn + 255) / 256, 128, 0, stream>>>(h, batch, sums, gcnt, Nn);
  pred_kernel<<<out_size, 128, 0, stream>>>(sums, gcnt, pw, pb, out);
}